// Round 2
// baseline (1788.834 us; speedup 1.0000x reference)
//
#include <hip/hip_runtime.h>
#include <math.h>

// ---- problem constants ----
static constexpr int B_    = 4;
static constexpr int C_    = 192;
static constexpr int HID_  = 768;
static constexpr int H_    = 128;
static constexpr int W_    = 128;
static constexpr int NPIX  = H_ * W_;          // 16384
static constexpr int PTOT  = B_ * NPIX;        // 65536
static constexpr int HEADS = 6;
static constexpr int CHD   = 32;               // head dim
static constexpr int WSZ   = 8;
static constexpr int STR   = 6;
static constexpr int LH    = 22;               // (128+6-8)/6+1
static constexpr int LWIN  = LH * LH;          // 484
static constexpr int NWIN  = B_ * LWIN;        // 1936

// ============================================================
// LN stats: per pixel over Cn channels (layout [b][Cn][NPIX])
// ============================================================
__global__ __launch_bounds__(256) void ln_stats_k(const float* __restrict__ in, int Cn,
                                                  float* __restrict__ mu, float* __restrict__ rs) {
    int p = blockIdx.x * 256 + threadIdx.x;
    if (p >= PTOT) return;
    int b = p >> 14, n = p & (NPIX - 1);
    const float* base = in + (size_t)b * Cn * NPIX + n;
    float s = 0.f, s2 = 0.f;
    for (int c = 0; c < Cn; ++c) {
        float v = base[(size_t)c * NPIX];
        s += v; s2 += v * v;
    }
    float m = s / Cn;
    float var = s2 / Cn - m * m;
    mu[p] = m;
    rs[p] = rsqrtf(var + 1e-5f);
}

// ============================================================
// prep: wg = W*g ; wsum = sum_c wg ; wb = sum_c W*bln + bias
// ============================================================
__global__ __launch_bounds__(256) void prep_k(const float* __restrict__ W, const float* __restrict__ g,
                                              const float* __restrict__ bln, const float* __restrict__ bias,
                                              int M, int K,
                                              float* __restrict__ wg, float* __restrict__ wsum,
                                              float* __restrict__ wb) {
    int o = blockIdx.x * 256 + threadIdx.x;
    if (o >= M) return;
    float sum = 0.f, bb = 0.f;
    for (int c = 0; c < K; ++c) {
        float wv = W[(size_t)o * K + c];
        float wgv = wv * g[c];
        wg[(size_t)o * K + c] = wgv;
        sum += wgv;
        bb += wv * bln[c];
    }
    wsum[o] = sum;
    wb[o] = bb + bias[o];
}

// ============================================================
// GEMM: out[b][o][n] = act( dot(W[o,:], in[b,:,n]) + ... )
// LN-fused: val = rs_p*acc - mu_p*rs_p*wsum[o] + wb[o]
// plain   : val = acc + wb[o]
// ACT: 0=none, 1=exact GELU.  RES: add resid (same layout as out).
// M % 64 == 0, K % 16 == 0.  gridDim.x MUST be PTOT/64 = 1024.
// ============================================================
template <int ACT, bool LN, bool RES>
__global__ __launch_bounds__(256) void gemm_k(const float* __restrict__ W, const float* __restrict__ in,
                                              float* __restrict__ out,
                                              const float* __restrict__ mu, const float* __restrict__ rs,
                                              const float* __restrict__ wsum, const float* __restrict__ wb,
                                              const float* __restrict__ resid, int M, int K) {
    __shared__ float Ws[16][72];   // [kk][o_local], stride 72 (16B-aligned rows)
    __shared__ float Xs[16][64];   // [kk][n_local]
    int pt = blockIdx.x;           // pixel tile 0..1023
    int b  = pt >> 8;              // 256 tiles per image
    int n0 = (pt & 255) << 6;
    int o0 = blockIdx.y << 6;
    int t  = threadIdx.x;
    int tx = t & 15, ty = t >> 4;
    float acc[4][4] = {{0.f}};
    const float* inb = in + (size_t)b * K * NPIX;

    for (int k0 = 0; k0 < K; k0 += 16) {
        {   // W tile: 64 rows x 16 k
            int r = t >> 2, c4 = (t & 3) << 2;
            const float4 wv = *(const float4*)(W + (size_t)(o0 + r) * K + k0 + c4);
            Ws[c4 + 0][r] = wv.x; Ws[c4 + 1][r] = wv.y;
            Ws[c4 + 2][r] = wv.z; Ws[c4 + 3][r] = wv.w;
        }
        {   // X tile: 16 k x 64 n
            int col = t & 63, r0 = t >> 6;
            for (int it = 0; it < 4; ++it) {
                int kk = r0 + (it << 2);
                Xs[kk][col] = inb[(size_t)(k0 + kk) * NPIX + n0 + col];
            }
        }
        __syncthreads();
        for (int kk = 0; kk < 16; ++kk) {
            float4 xq = *(const float4*)&Xs[kk][tx << 2];
            float4 wq = *(const float4*)&Ws[kk][ty << 2];
            float xv[4] = {xq.x, xq.y, xq.z, xq.w};
            float wv[4] = {wq.x, wq.y, wq.z, wq.w};
            #pragma unroll
            for (int i = 0; i < 4; ++i)
                #pragma unroll
                for (int j = 0; j < 4; ++j)
                    acc[i][j] += wv[i] * xv[j];
        }
        __syncthreads();
    }

    int nbase = n0 + (tx << 2);
    int pbase = (b << 14) + nbase;
    float4 muv = {0,0,0,0}, rsv = {1,1,1,1};
    if (LN) {
        muv = *(const float4*)(mu + pbase);
        rsv = *(const float4*)(rs + pbase);
    }
    float mus[4] = {muv.x, muv.y, muv.z, muv.w};
    float rss[4] = {rsv.x, rsv.y, rsv.z, rsv.w};
    #pragma unroll
    for (int i = 0; i < 4; ++i) {
        int o = o0 + (ty << 2) + i;
        float wbv = wb[o];
        float wsv = LN ? wsum[o] : 0.f;
        size_t oi = ((size_t)b * M + o) * NPIX + nbase;
        float4 res;
        if (RES) res = *(const float4*)(resid + oi);
        float vout[4];
        #pragma unroll
        for (int j = 0; j < 4; ++j) {
            float v;
            if (LN) v = rss[j] * acc[i][j] - mus[j] * rss[j] * wsv + wbv;
            else    v = acc[i][j] + wbv;
            if (ACT == 1) v = 0.5f * v * (1.f + erff(v * 0.70710678118654752f));
            vout[j] = v;
        }
        if (RES) { vout[0]+=res.x; vout[1]+=res.y; vout[2]+=res.z; vout[3]+=res.w; }
        float4 ov = {vout[0], vout[1], vout[2], vout[3]};
        *(float4*)(out + oi) = ov;
    }
}

// ============================================================
// attention: one block per (window, head)
// ============================================================
__global__ __launch_bounds__(256) void attn_k(const float* __restrict__ qkv, const float* __restrict__ rpb,
                                              const float* __restrict__ temp,
                                              float* __restrict__ o_win, float* __restrict__ s_win) {
    __shared__ float qs[64][33];
    __shared__ float ks[64][33];
    __shared__ float vs[64][33];
    __shared__ float es[64][65];
    __shared__ float rp[225];
    int wh = blockIdx.x;               // (b*LWIN + l)*HEADS + head
    int head = wh % HEADS;
    int bw = wh / HEADS;
    int b = bw / LWIN, l = bw % LWIN;
    int sh = l / LH, sw = l % LH;
    int h0 = sh * STR - 3, w0 = sw * STR - 3;
    int t = threadIdx.x;
    float tmp = temp[head];
    if (t < 225) rp[t] = rpb[t * HEADS + head];

    for (int r = 0; r < 3; ++r) {
        for (int jj = 0; jj < 8; ++jj) {
            int ei = t + (jj << 8);
            int cc = ei >> 6, idx = ei & 63;
            int iy = idx >> 3, ix = idx & 7;
            int hh = h0 + iy, wwp = w0 + ix;
            float val = 0.f;
            if ((unsigned)hh < 128u && (unsigned)wwp < 128u)
                val = qkv[(size_t)(b * 576 + r * 192 + head * 32 + cc) * NPIX + (hh << 7) + wwp];
            if (r == 0)      qs[idx][cc] = val * tmp;
            else if (r == 1) ks[idx][cc] = val;
            else             vs[idx][cc] = val;
        }
    }
    __syncthreads();

    int i = t >> 2, jg = t & 3;
    float ev[16];
    float mx = -1e30f;
    #pragma unroll
    for (int jj = 0; jj < 16; ++jj) {
        int j = (jg << 4) + jj;
        float d = 0.f;
        #pragma unroll
        for (int cc = 0; cc < 32; ++cc) d += qs[i][cc] * ks[j][cc];
        int dy = (i >> 3) - (j >> 3) + 7;
        int dx = (i & 7) - (j & 7) + 7;
        d += rp[dy * 15 + dx];
        ev[jj] = d;
        mx = fmaxf(mx, d);
    }
    mx = fmaxf(mx, __shfl_xor(mx, 1));
    mx = fmaxf(mx, __shfl_xor(mx, 2));
    float sum = 0.f;
    #pragma unroll
    for (int jj = 0; jj < 16; ++jj) {
        float ee = expf(ev[jj] - mx);
        es[i][(jg << 4) + jj] = ee;
        sum += ee;
    }
    sum += __shfl_xor(sum, 1);
    sum += __shfl_xor(sum, 2);
    if (jg == 0) s_win[(size_t)wh * 64 + i] = sum;
    __syncthreads();

    int c = t & 31, i0 = t >> 5;
    for (int rr = 0; rr < 8; ++rr) {
        int ii = (i0 << 3) + rr;
        float acc = 0.f;
        #pragma unroll
        for (int j = 0; j < 64; ++j) acc += es[ii][j] * vs[j][c];
        o_win[(size_t)wh * 2048 + (ii << 5) + c] = acc;
    }
}

// ============================================================
// s_img gather-fold: (B,HEADS,H,W)
// ============================================================
__device__ __forceinline__ void win_range(int h, int& s0, int& s1) {
    s0 = (h + 1) / 6; if (s0 < 0) s0 = 0;
    s1 = (h + 3) / 6; if (s1 > 21) s1 = 21;
}

__global__ __launch_bounds__(256) void simg_k(const float* __restrict__ s_win, float* __restrict__ s_img) {
    int tid = blockIdx.x * 256 + threadIdx.x;
    if (tid >= B_ * HEADS * NPIX) return;
    int n = tid & (NPIX - 1);
    int bh = tid >> 14;
    int hd = bh % HEADS, b = bh / HEADS;
    int hy = n >> 7, wx = n & 127;
    int sy0, sy1, sx0, sx1;
    win_range(hy, sy0, sy1);
    win_range(wx, sx0, sx1);
    float acc = 0.f;
    for (int sy = sy0; sy <= sy1; ++sy)
        for (int sx = sx0; sx <= sx1; ++sx) {
            int idx = (hy - (sy * 6 - 3)) * 8 + (wx - (sx * 6 - 3));
            acc += s_win[(size_t)((b * LWIN + sy * LH + sx) * HEADS + hd) * 64 + idx];
        }
    s_img[tid] = acc;
}

// ============================================================
// fold o + divide: attn_out[b][c][n]
// ============================================================
__global__ __launch_bounds__(256) void fold_k(const float* __restrict__ o_win, const float* __restrict__ s_img,
                                              float* __restrict__ attn_out) {
    int tid = blockIdx.x * 256 + threadIdx.x;
    if (tid >= B_ * C_ * NPIX) return;
    int n = tid & (NPIX - 1);
    int bc = tid >> 14;
    int ch = bc % C_, b = bc / C_;
    int hd = ch >> 5, cc = ch & 31;
    int hy = n >> 7, wx = n & 127;
    int sy0, sy1, sx0, sx1;
    win_range(hy, sy0, sy1);
    win_range(wx, sx0, sx1);
    float acc = 0.f;
    for (int sy = sy0; sy <= sy1; ++sy)
        for (int sx = sx0; sx <= sx1; ++sx) {
            int idx = (hy - (sy * 6 - 3)) * 8 + (wx - (sx * 6 - 3));
            acc += o_win[((size_t)((b * LWIN + sy * LH + sx) * HEADS + hd) * 64 + idx) * 32 + cc];
        }
    attn_out[tid] = acc / s_img[((b * HEADS + hd) << 14) + n];
}

// ============================================================
// 2x2 average pooling (generic halving), per bc channel image
// ============================================================
__global__ __launch_bounds__(256) void halve_k(const float* __restrict__ in, float* __restrict__ out, int Win) {
    int Wo = Win >> 1;
    int tot = B_ * C_ * Wo * Wo;
    int tid = blockIdx.x * 256 + threadIdx.x;
    if (tid >= tot) return;
    int xy = tid % (Wo * Wo);
    int bc = tid / (Wo * Wo);
    int y = xy / Wo, x = xy % Wo;
    const float* p = in + (size_t)bc * Win * Win + (size_t)(2 * y) * Win + 2 * x;
    out[tid] = 0.25f * (p[0] + p[1] + p[Win] + p[Win + 1]);
}

// a = 3*po - up(p2) - up(p4) - up(p8)
__global__ __launch_bounds__(256) void hfa_k(const float* __restrict__ po, const float* __restrict__ p2,
                                             const float* __restrict__ p4, const float* __restrict__ p8,
                                             float* __restrict__ a) {
    int tid = blockIdx.x * 256 + threadIdx.x;
    if (tid >= B_ * C_ * NPIX) return;
    int n = tid & (NPIX - 1);
    int bc = tid >> 14;
    int y = n >> 7, x = n & 127;
    float v = 3.f * po[tid]
            - p2[((size_t)bc << 12) + ((y >> 1) << 6) + (x >> 1)]
            - p4[((size_t)bc << 10) + ((y >> 2) << 5) + (x >> 2)]
            - p8[((size_t)bc << 8)  + ((y >> 3) << 4) + (x >> 3)];
    a[tid] = v;
}

// x1 = x + sigmoid(dwconv3(a)) * po
__global__ __launch_bounds__(256) void hft_k(const float* __restrict__ a, const float* __restrict__ po,
                                             const float* __restrict__ x, const float* __restrict__ hw,
                                             const float* __restrict__ hb, float* __restrict__ x1) {
    int tid = blockIdx.x * 256 + threadIdx.x;
    if (tid >= B_ * C_ * NPIX) return;
    int n = tid & (NPIX - 1);
    int bc = tid >> 14;
    int ch = bc % C_;
    int y = n >> 7, xx = n & 127;
    const float* ab = a + ((size_t)bc << 14);
    float acc = hb[ch];
    #pragma unroll
    for (int dy = 0; dy < 3; ++dy) {
        int yy = y + dy - 1;
        if ((unsigned)yy >= 128u) continue;
        #pragma unroll
        for (int dx = 0; dx < 3; ++dx) {
            int xw = xx + dx - 1;
            if ((unsigned)xw >= 128u) continue;
            acc += hw[ch * 9 + dy * 3 + dx] * ab[(yy << 7) + xw];
        }
    }
    float sg = 1.f / (1.f + expf(-acc));
    x1[tid] = x[tid] + sg * po[tid];
}

// z1 *= dwconv3( LN(z2) )   (SimpleGate)
__global__ __launch_bounds__(256) void sgmul_k(const float* __restrict__ z2, const float* __restrict__ mu3,
                                               const float* __restrict__ rs3, const float* __restrict__ sgn_g,
                                               const float* __restrict__ sgn_b, const float* __restrict__ sg_w,
                                               const float* __restrict__ sg_b, float* __restrict__ z1) {
    int tid = blockIdx.x * 256 + threadIdx.x;
    if (tid >= B_ * 384 * NPIX) return;
    int n = tid & (NPIX - 1);
    int bc = tid >> 14;
    int ch = bc % 384, b = bc / 384;
    int y = n >> 7, xx = n & 127;
    const float* zb = z2 + ((size_t)bc << 14);
    const float* mub = mu3 + (b << 14);
    const float* rsb = rs3 + (b << 14);
    float g = sgn_g[ch], bb = sgn_b[ch];
    float acc = sg_b[ch];
    #pragma unroll
    for (int dy = 0; dy < 3; ++dy) {
        int yy = y + dy - 1;
        if ((unsigned)yy >= 128u) continue;
        #pragma unroll
        for (int dx = 0; dx < 3; ++dx) {
            int xw = xx + dx - 1;
            if ((unsigned)xw >= 128u) continue;
            int nn = (yy << 7) + xw;
            float val = (zb[nn] - mub[nn]) * rsb[nn] * g + bb;
            acc += sg_w[ch * 9 + dy * 3 + dx] * val;
        }
    }
    z1[tid] *= acc;
}

// ============================================================
extern "C" void kernel_launch(void* const* d_in, const int* in_sizes, int n_in,
                              void* d_out, int out_size, void* d_ws, size_t ws_size,
                              hipStream_t stream) {
    const float* x     = (const float*)d_in[0];
    const float* n1g   = (const float*)d_in[1];
    const float* n1b   = (const float*)d_in[2];
    const float* qkv_w = (const float*)d_in[3];
    const float* qkv_b = (const float*)d_in[4];
    const float* temp  = (const float*)d_in[5];
    const float* rpb   = (const float*)d_in[6];
    const float* proj_w= (const float*)d_in[7];
    const float* proj_b= (const float*)d_in[8];
    const float* hft_w = (const float*)d_in[9];
    const float* hft_b = (const float*)d_in[10];
    const float* n2g   = (const float*)d_in[11];
    const float* n2b   = (const float*)d_in[12];
    const float* fc1_w = (const float*)d_in[13];
    const float* fc1_b = (const float*)d_in[14];
    const float* sgn_g = (const float*)d_in[15];
    const float* sgn_b = (const float*)d_in[16];
    const float* sg_w  = (const float*)d_in[17];
    const float* sg_b  = (const float*)d_in[18];
    const float* fc2_w = (const float*)d_in[19];
    const float* fc2_b = (const float*)d_in[20];
    float* out = (float*)d_out;
    float* w = (float*)d_ws;

    // ---- workspace layout (floats) ----
    float* mu1 = w;                 float* rs1 = w + 65536;
    float* mu2 = w + 131072;        float* rs2 = w + 196608;
    float* mu3 = w + 262144;        float* rs3 = w + 327680;
    float* wg_qkv  = w + 393216;                 // 576*192 = 110592
    float* wsum_qkv = wg_qkv + 110592;           // 576
    float* wb_qkv   = wsum_qkv + 576;            // 576
    float* wg_fc1   = wb_qkv + 576;              // 768*192 = 147456
    float* wsum_fc1 = wg_fc1 + 147456;           // 768
    float* wb_fc1   = wsum_fc1 + 768;            // 768
    float* big1 = wb_fc1 + 768;                  // 576*PTOT = 37,748,736
    float* big2 = big1 + 37748736;               // 25,165,824
    // aliases on big1:
    float* qkv      = big1;                      // 576*PTOT (stage A/B)
    float* attn_out = big1;                      // 192*PTOT (stage C+)
    float* proj_out = big1 + 12582912;           // 192*PTOT
    float* x1       = big1 + 25165824;           // 192*PTOT (persists)
    float* z1       = big1;                      // 384*PTOT (stage F)
    // aliases on big2:
    float* o_win = big2;                         // 1936*6*64*32 = 23,789,568
    float* s_win = big2 + 23789568;              // 743,424
    float* s_img = s_win + 743424;               // 393,216
    float* p2    = big2;                         // 3,145,728 (stage E)
    float* p4    = p2 + 3145728;                 // 786,432
    float* p8    = p4 + 786432;                  // 196,608
    float* abuf  = p8 + 196608;                  // 12,582,912
    float* z2    = big2;                         // 384*PTOT (stage F)

    // ---- stage A: LN1 + qkv GEMM ----
    ln_stats_k<<<256, 256, 0, stream>>>(x, 192, mu1, rs1);
    prep_k<<<3, 256, 0, stream>>>(qkv_w, n1g, n1b, qkv_b, 576, 192, wg_qkv, wsum_qkv, wb_qkv);
    gemm_k<0, true, false><<<dim3(1024, 9), 256, 0, stream>>>(wg_qkv, x, qkv, mu1, rs1,
                                                              wsum_qkv, wb_qkv, nullptr, 576, 192);
    // ---- stage B: window attention ----
    attn_k<<<NWIN * HEADS, 256, 0, stream>>>(qkv, rpb, temp, o_win, s_win);
    // ---- stage C: fold ----
    simg_k<<<1536, 256, 0, stream>>>(s_win, s_img);
    fold_k<<<49152, 256, 0, stream>>>(o_win, s_img, attn_out);
    // ---- stage D: proj ----
    gemm_k<0, false, false><<<dim3(1024, 3), 256, 0, stream>>>(proj_w, attn_out, proj_out,
                                                               nullptr, nullptr, nullptr, proj_b, nullptr, 192, 192);
    // ---- stage E: HFT + residual -> x1 ----
    halve_k<<<12288, 256, 0, stream>>>(proj_out, p2, 128);
    halve_k<<<3072, 256, 0, stream>>>(p2, p4, 64);
    halve_k<<<768, 256, 0, stream>>>(p4, p8, 32);
    hfa_k<<<49152, 256, 0, stream>>>(proj_out, p2, p4, p8, abuf);
    hft_k<<<49152, 256, 0, stream>>>(abuf, proj_out, x, hft_w, hft_b, x1);
    // ---- stage F: LN2 + fc1 + GELU -> z1, z2 ----
    ln_stats_k<<<256, 256, 0, stream>>>(x1, 192, mu2, rs2);
    prep_k<<<3, 256, 0, stream>>>(fc1_w, n2g, n2b, fc1_b, 768, 192, wg_fc1, wsum_fc1, wb_fc1);
    gemm_k<1, true, false><<<dim3(1024, 6), 256, 0, stream>>>(wg_fc1, x1, z1, mu2, rs2,
                                                              wsum_fc1, wb_fc1, nullptr, 384, 192);
    gemm_k<1, true, false><<<dim3(1024, 6), 256, 0, stream>>>(wg_fc1 + 73728, x1, z2, mu2, rs2,
                                                              wsum_fc1 + 384, wb_fc1 + 384, nullptr, 384, 192);
    // ---- stage G: SimpleGate ----
    ln_stats_k<<<256, 256, 0, stream>>>(z2, 384, mu3, rs3);
    sgmul_k<<<98304, 256, 0, stream>>>(z2, mu3, rs3, sgn_g, sgn_b, sg_w, sg_b, z1);
    // ---- stage H: fc2 + residual -> out ----
    gemm_k<0, false, true><<<dim3(1024, 3), 256, 0, stream>>>(fc2_w, z1, out,
                                                              nullptr, nullptr, nullptr, fc2_b, x1, 192, 384);
}

// Round 3
// 1219.677 us; speedup vs baseline: 1.4666x; 1.4666x over previous
//
#include <hip/hip_runtime.h>
#include <math.h>

// ---- problem constants ----
static constexpr int B_    = 4;
static constexpr int C_    = 192;
static constexpr int NPIX  = 16384;            // 128*128
static constexpr int PTOT  = B_ * NPIX;        // 65536
static constexpr int HEADS = 6;
static constexpr int STR   = 6;
static constexpr int LH    = 22;
static constexpr int LWIN  = LH * LH;          // 484
static constexpr int NWIN  = B_ * LWIN;        // 1936

typedef short bf16x8 __attribute__((ext_vector_type(8)));
typedef float f32x4  __attribute__((ext_vector_type(4)));

__device__ __forceinline__ unsigned short f2bf(float f) {
    union { float f; unsigned int u; } v; v.f = f;
    unsigned int r = v.u + 0x7FFFu + ((v.u >> 16) & 1u);
    return (unsigned short)(r >> 16);
}
__device__ __forceinline__ float bf2f(unsigned short h) {
    union { unsigned int u; float f; } v; v.u = ((unsigned int)h) << 16;
    return v.f;
}

// ============================================================
// LN stats per pixel over Cn channels. in layout [b][*][NPIX],
// image stride bstride elements, channel rows contiguous NPIX.
// ============================================================
template <typename T>
__global__ __launch_bounds__(256) void ln_stats_k(const T* __restrict__ in, int Cn, int bstride,
                                                  float* __restrict__ mu, float* __restrict__ rs) {
    int p = blockIdx.x * 256 + threadIdx.x;
    if (p >= PTOT) return;
    int b = p >> 14, n = p & (NPIX - 1);
    const T* base = in + (size_t)b * bstride + n;
    float s = 0.f, s2 = 0.f;
    for (int c = 0; c < Cn; ++c) {
        float v;
        if constexpr (sizeof(T) == 2) v = bf2f(base[(size_t)c * NPIX]);
        else                          v = base[(size_t)c * NPIX];
        s += v; s2 += v * v;
    }
    float m = s / Cn;
    float var = s2 / Cn - m * m;
    mu[p] = m;
    rs[p] = rsqrtf(var + 1e-5f);
}

// ============================================================
// prep: wgb = bf16(W*g); wsum = sum(W*g); wb = W·bln + bias
// ============================================================
__global__ __launch_bounds__(256) void prep_k(const float* __restrict__ W, const float* __restrict__ g,
                                              const float* __restrict__ bln, const float* __restrict__ bias,
                                              int M, int K,
                                              unsigned short* __restrict__ wgb, float* __restrict__ wsum,
                                              float* __restrict__ wb) {
    int o = blockIdx.x * 256 + threadIdx.x;
    if (o >= M) return;
    float sum = 0.f, bb = 0.f;
    for (int c = 0; c < K; ++c) {
        float wv = W[(size_t)o * K + c];
        float wgv = wv * g[c];
        wgb[(size_t)o * K + c] = f2bf(wgv);
        sum += wgv;
        bb += wv * bln[c];
    }
    wsum[o] = sum;
    wb[o] = bb + bias[o];
}

// plain fp32 -> bf16 convert
__global__ __launch_bounds__(256) void wcvt_k(const float* __restrict__ W, unsigned short* __restrict__ Wb, int n) {
    int i = blockIdx.x * 256 + threadIdx.x;
    if (i < n) Wb[i] = f2bf(W[i]);
}

// ============================================================
// transpose-convert: [Cn][NPIX] (T) -> [NPIX][Cn] bf16, per image
// grid (NPIX/64, Cn/64, B); image stride of input = bstride elems
// ============================================================
template <typename T>
__global__ __launch_bounds__(256) void transpose_k(const T* __restrict__ in, unsigned short* __restrict__ out,
                                                   int Cn, int bstride) {
    __shared__ float tile[64][65];
    int n0 = blockIdx.x << 6, c0 = blockIdx.y << 6, b = blockIdx.z;
    int t = threadIdx.x, r = t >> 2, cg = (t & 3) << 4;
    const T* ib = in + (size_t)b * bstride;
    if constexpr (sizeof(T) == 4) {
        const float4* src = (const float4*)(ib + (size_t)(c0 + r) * NPIX + n0 + cg);
        #pragma unroll
        for (int j = 0; j < 4; ++j) {
            float4 v = src[j];
            tile[r][cg + 4 * j + 0] = v.x; tile[r][cg + 4 * j + 1] = v.y;
            tile[r][cg + 4 * j + 2] = v.z; tile[r][cg + 4 * j + 3] = v.w;
        }
    } else {
        const uint4* src = (const uint4*)((const unsigned short*)ib + (size_t)(c0 + r) * NPIX + n0 + cg);
        uint4 v0 = src[0], v1 = src[1];
        unsigned int arr[8] = {v0.x, v0.y, v0.z, v0.w, v1.x, v1.y, v1.z, v1.w};
        #pragma unroll
        for (int j = 0; j < 8; ++j) {
            tile[r][cg + 2 * j]     = bf2f((unsigned short)(arr[j] & 0xFFFFu));
            tile[r][cg + 2 * j + 1] = bf2f((unsigned short)(arr[j] >> 16));
        }
    }
    __syncthreads();
    unsigned int pk[8];
    #pragma unroll
    for (int j = 0; j < 8; ++j) {
        unsigned int lo = f2bf(tile[cg + 2 * j][r]);
        unsigned int hi = f2bf(tile[cg + 2 * j + 1][r]);
        pk[j] = lo | (hi << 16);
    }
    uint4* dst = (uint4*)(out + ((size_t)(b << 14) + n0 + r) * Cn + c0 + cg);
    dst[0] = make_uint4(pk[0], pk[1], pk[2], pk[3]);
    dst[1] = make_uint4(pk[4], pk[5], pk[6], pk[7]);
}

// ============================================================
// MFMA GEMM: out[b][o][n] = epilogue( sum_k W[o][k] * Xt[b][n][k] )
// Xt bf16 [b][NPIX][KK]; Wb bf16 [M][KK]; 256 thr = 4 waves (2x2)
// tile: PIXT pixels x 64 outputs.  D frag: row=pixel, col=o.
// ============================================================
template <int KK, int PIXT, int ACT, bool LN, bool RES, bool OBF>
__global__ __launch_bounds__(256) void gemm_mfma_k(const unsigned short* __restrict__ Wb,
                                                   const unsigned short* __restrict__ Xt,
                                                   void* __restrict__ outv,
                                                   const float* __restrict__ mu, const float* __restrict__ rs,
                                                   const float* __restrict__ wsum, const float* __restrict__ wb,
                                                   const float* __restrict__ resid, int M) {
    constexpr int LDK    = KK + 8;          // padded LDS row (halfs)
    constexpr int KSTEPS = KK / 32;
    constexpr int MREP   = PIXT / 32;       // frags per wave in pixel dim
    constexpr int NREP   = 2;               // frags per wave in o dim
    __shared__ unsigned short xs[PIXT * LDK];

    int t = threadIdx.x;
    int gp = blockIdx.x * PIXT;
    int b  = gp >> 14;
    int n0 = gp & (NPIX - 1);
    int o0 = blockIdx.y << 6;

    // ---- stage Xt tile into padded LDS (12 chunks of 16B per thread) ----
    const unsigned short* xg = Xt + (size_t)(b * NPIX + n0) * KK;
    constexpr int NJ = KK / 8;
    #pragma unroll
    for (int i = 0; i < PIXT * NJ / 256; ++i) {
        int c = i * 256 + t;
        int p, j;
        if (KK == 192) { p = (c * 2731) >> 16; j = c - p * 24; }
        else           { int q = c >> 4; p = (q * 21846) >> 16; j = c - p * 48; }
        uint4 v = *(const uint4*)(xg + (size_t)p * KK + j * 8);
        *(uint4*)&xs[p * LDK + j * 8] = v;
    }
    __syncthreads();

    int w  = t >> 6, l = t & 63;
    int wr = w >> 1, wc = w & 1;
    int lr = l & 15, kb = l >> 4;
    int pw = wr * (PIXT / 2);
    int ow = o0 + wc * 32;

    f32x4 acc[MREP][NREP];
    #pragma unroll
    for (int m = 0; m < MREP; ++m)
        #pragma unroll
        for (int n = 0; n < NREP; ++n) acc[m][n] = (f32x4){0.f, 0.f, 0.f, 0.f};

    #pragma unroll
    for (int ks = 0; ks < KSTEPS; ++ks) {
        int k0 = ks * 32;
        bf16x8 bfr[NREP];
        #pragma unroll
        for (int n = 0; n < NREP; ++n) {
            int o = ow + n * 16 + lr;
            bfr[n] = *(const bf16x8*)(Wb + (size_t)o * KK + k0 + kb * 8);
        }
        bf16x8 afr[MREP];
        #pragma unroll
        for (int m = 0; m < MREP; ++m) {
            int p = pw + m * 16 + lr;
            afr[m] = *(const bf16x8*)&xs[p * LDK + k0 + kb * 8];
        }
        #pragma unroll
        for (int m = 0; m < MREP; ++m)
            #pragma unroll
            for (int n = 0; n < NREP; ++n)
                acc[m][n] = __builtin_amdgcn_mfma_f32_16x16x32_bf16(afr[m], bfr[n], acc[m][n], 0, 0, 0);
    }

    // ---- epilogue ----
    #pragma unroll
    for (int m = 0; m < MREP; ++m) {
        int prow = pw + m * 16 + kb * 4;
        int nidx = n0 + prow;
        float muv[4], rsv[4];
        if (LN) {
            #pragma unroll
            for (int r = 0; r < 4; ++r) {
                muv[r] = mu[(b << 14) + nidx + r];
                rsv[r] = rs[(b << 14) + nidx + r];
            }
        }
        #pragma unroll
        for (int n = 0; n < NREP; ++n) {
            int o = ow + n * 16 + lr;
            float wbv = wb[o];
            float wsv = 0.f; if (LN) wsv = wsum[o];
            size_t obase = (((size_t)b * M + o) << 14) + nidx;
            float rv[4] = {0.f, 0.f, 0.f, 0.f};
            if (RES) {
                float4 rr = *(const float4*)(resid + obase);
                rv[0] = rr.x; rv[1] = rr.y; rv[2] = rr.z; rv[3] = rr.w;
            }
            float vo[4];
            #pragma unroll
            for (int r = 0; r < 4; ++r) {
                float a = acc[m][n][r];
                float v = LN ? (rsv[r] * a - muv[r] * rsv[r] * wsv + wbv) : (a + wbv);
                if (ACT == 1) v = 0.5f * v * (1.f + erff(v * 0.70710678118654752f));
                vo[r] = v + rv[r];
            }
            if (OBF) {
                ushort4 u;
                u.x = f2bf(vo[0]); u.y = f2bf(vo[1]); u.z = f2bf(vo[2]); u.w = f2bf(vo[3]);
                *(ushort4*)((unsigned short*)outv + obase) = u;
            } else {
                float4 f = {vo[0], vo[1], vo[2], vo[3]};
                *(float4*)((float*)outv + obase) = f;
            }
        }
    }
}

// ============================================================
// attention: one block per (window, head); qkv is bf16
// ============================================================
__global__ __launch_bounds__(256) void attn_k(const unsigned short* __restrict__ qkv,
                                              const float* __restrict__ rpb,
                                              const float* __restrict__ temp,
                                              float* __restrict__ o_win, float* __restrict__ s_win) {
    __shared__ float qs[64][33];
    __shared__ float ks[64][33];
    __shared__ float vs[64][33];
    __shared__ float es[64][65];
    __shared__ float rp[225];
    int wh = blockIdx.x;
    int head = wh % HEADS;
    int bw = wh / HEADS;
    int b = bw / LWIN, l = bw % LWIN;
    int sh = l / LH, sw = l % LH;
    int h0 = sh * STR - 3, w0 = sw * STR - 3;
    int t = threadIdx.x;
    float tmp = temp[head];
    if (t < 225) rp[t] = rpb[t * HEADS + head];

    for (int r = 0; r < 3; ++r) {
        for (int jj = 0; jj < 8; ++jj) {
            int ei = t + (jj << 8);
            int cc = ei >> 6, idx = ei & 63;
            int iy = idx >> 3, ix = idx & 7;
            int hh = h0 + iy, wwp = w0 + ix;
            float val = 0.f;
            if ((unsigned)hh < 128u && (unsigned)wwp < 128u)
                val = bf2f(qkv[(size_t)(b * 576 + r * 192 + head * 32 + cc) * NPIX + (hh << 7) + wwp]);
            if (r == 0)      qs[idx][cc] = val * tmp;
            else if (r == 1) ks[idx][cc] = val;
            else             vs[idx][cc] = val;
        }
    }
    __syncthreads();

    int i = t >> 2, jg = t & 3;
    float ev[16];
    float mx = -1e30f;
    #pragma unroll
    for (int jj = 0; jj < 16; ++jj) {
        int j = (jg << 4) + jj;
        float d = 0.f;
        #pragma unroll
        for (int cc = 0; cc < 32; ++cc) d += qs[i][cc] * ks[j][cc];
        int dy = (i >> 3) - (j >> 3) + 7;
        int dx = (i & 7) - (j & 7) + 7;
        d += rp[dy * 15 + dx];
        ev[jj] = d;
        mx = fmaxf(mx, d);
    }
    mx = fmaxf(mx, __shfl_xor(mx, 1));
    mx = fmaxf(mx, __shfl_xor(mx, 2));
    float sum = 0.f;
    #pragma unroll
    for (int jj = 0; jj < 16; ++jj) {
        float ee = expf(ev[jj] - mx);
        es[i][(jg << 4) + jj] = ee;
        sum += ee;
    }
    sum += __shfl_xor(sum, 1);
    sum += __shfl_xor(sum, 2);
    if (jg == 0) s_win[(size_t)wh * 64 + i] = sum;
    __syncthreads();

    int c = t & 31, i0 = t >> 5;
    for (int rr = 0; rr < 8; ++rr) {
        int ii = (i0 << 3) + rr;
        float acc = 0.f;
        #pragma unroll
        for (int j = 0; j < 64; ++j) acc += es[ii][j] * vs[j][c];
        o_win[(size_t)wh * 2048 + (ii << 5) + c] = acc;
    }
}

// ============================================================
__device__ __forceinline__ void win_range(int h, int& s0, int& s1) {
    s0 = (h + 1) / 6; if (s0 < 0) s0 = 0;
    s1 = (h + 3) / 6; if (s1 > 21) s1 = 21;
}

__global__ __launch_bounds__(256) void simg_k(const float* __restrict__ s_win, float* __restrict__ s_img) {
    int tid = blockIdx.x * 256 + threadIdx.x;
    if (tid >= B_ * HEADS * NPIX) return;
    int n = tid & (NPIX - 1);
    int bh = tid >> 14;
    int hd = bh % HEADS, b = bh / HEADS;
    int hy = n >> 7, wx = n & 127;
    int sy0, sy1, sx0, sx1;
    win_range(hy, sy0, sy1);
    win_range(wx, sx0, sx1);
    float acc = 0.f;
    for (int sy = sy0; sy <= sy1; ++sy)
        for (int sx = sx0; sx <= sx1; ++sx) {
            int idx = (hy - (sy * 6 - 3)) * 8 + (wx - (sx * 6 - 3));
            acc += s_win[(size_t)((b * LWIN + sy * LH + sx) * HEADS + hd) * 64 + idx];
        }
    s_img[tid] = acc;
}

// ============================================================
// fold o + divide -> attn_t bf16 [b][n][192]  (thread = (b,n,oct8))
// ============================================================
__global__ __launch_bounds__(256) void fold_k(const float* __restrict__ o_win, const float* __restrict__ s_img,
                                              unsigned short* __restrict__ attn_t) {
    int tid = blockIdx.x * 256 + threadIdx.x;   // < 4*16384*24
    int q = (int)((((unsigned long long)(tid >> 3)) * 174763ull) >> 19);  // tid/24
    int oct = tid - q * 24;
    int n = q & (NPIX - 1), b = q >> 14;
    int hd = oct >> 2, c8 = (oct & 3) << 3;
    int hy = n >> 7, wx = n & 127;
    int sy0, sy1, sx0, sx1;
    win_range(hy, sy0, sy1);
    win_range(wx, sx0, sx1);
    float acc[8] = {0.f, 0.f, 0.f, 0.f, 0.f, 0.f, 0.f, 0.f};
    for (int sy = sy0; sy <= sy1; ++sy)
        for (int sx = sx0; sx <= sx1; ++sx) {
            int idx = (hy - (sy * 6 - 3)) * 8 + (wx - (sx * 6 - 3));
            const float* p = o_win + ((size_t)((b * LWIN + sy * LH + sx) * HEADS + hd) * 2048 + idx * 32 + c8);
            float4 a0 = *(const float4*)p;
            float4 a1 = *(const float4*)(p + 4);
            acc[0] += a0.x; acc[1] += a0.y; acc[2] += a0.z; acc[3] += a0.w;
            acc[4] += a1.x; acc[5] += a1.y; acc[6] += a1.z; acc[7] += a1.w;
        }
    float inv = 1.f / s_img[((b * HEADS + hd) << 14) + n];
    unsigned int pk[4];
    #pragma unroll
    for (int j = 0; j < 4; ++j) {
        unsigned int lo = f2bf(acc[2 * j] * inv);
        unsigned int hi = f2bf(acc[2 * j + 1] * inv);
        pk[j] = lo | (hi << 16);
    }
    *(uint4*)&attn_t[((size_t)((b << 14) + n)) * 192 + hd * 32 + c8] = make_uint4(pk[0], pk[1], pk[2], pk[3]);
}

// ============================================================
// HFT chain (proj_out fp32 [b][192][NPIX])
// ============================================================
__global__ __launch_bounds__(256) void halve_k(const float* __restrict__ in, float* __restrict__ out, int Win) {
    int Wo = Win >> 1;
    int tot = B_ * C_ * Wo * Wo;
    int tid = blockIdx.x * 256 + threadIdx.x;
    if (tid >= tot) return;
    int xy = tid % (Wo * Wo);
    int bc = tid / (Wo * Wo);
    int y = xy / Wo, x = xy % Wo;
    const float* p = in + (size_t)bc * Win * Win + (size_t)(2 * y) * Win + 2 * x;
    out[tid] = 0.25f * (p[0] + p[1] + p[Win] + p[Win + 1]);
}

__global__ __launch_bounds__(256) void hfa_k(const float* __restrict__ po, const float* __restrict__ p2,
                                             const float* __restrict__ p4, const float* __restrict__ p8,
                                             float* __restrict__ a) {
    int tid = blockIdx.x * 256 + threadIdx.x;
    if (tid >= B_ * C_ * NPIX) return;
    int n = tid & (NPIX - 1);
    int bc = tid >> 14;
    int y = n >> 7, x = n & 127;
    float v = 3.f * po[tid]
            - p2[((size_t)bc << 12) + ((y >> 1) << 6) + (x >> 1)]
            - p4[((size_t)bc << 10) + ((y >> 2) << 5) + (x >> 2)]
            - p8[((size_t)bc << 8)  + ((y >> 3) << 4) + (x >> 3)];
    a[tid] = v;
}

__global__ __launch_bounds__(256) void hft_k(const float* __restrict__ a, const float* __restrict__ po,
                                             const float* __restrict__ x, const float* __restrict__ hw,
                                             const float* __restrict__ hb, float* __restrict__ x1) {
    int tid = blockIdx.x * 256 + threadIdx.x;
    if (tid >= B_ * C_ * NPIX) return;
    int n = tid & (NPIX - 1);
    int bc = tid >> 14;
    int ch = bc % C_;
    int y = n >> 7, xx = n & 127;
    const float* ab = a + ((size_t)bc << 14);
    float acc = hb[ch];
    #pragma unroll
    for (int dy = 0; dy < 3; ++dy) {
        int yy = y + dy - 1;
        if ((unsigned)yy >= 128u) continue;
        #pragma unroll
        for (int dx = 0; dx < 3; ++dx) {
            int xw = xx + dx - 1;
            if ((unsigned)xw >= 128u) continue;
            acc += hw[ch * 9 + dy * 3 + dx] * ab[(yy << 7) + xw];
        }
    }
    float sg = 1.f / (1.f + expf(-acc));
    x1[tid] = x[tid] + sg * po[tid];
}

// ============================================================
// SimpleGate on bf16 z: z1 *= dwconv3(LN(z2));  z = [b][768][NPIX] bf16
// ============================================================
__global__ __launch_bounds__(256) void sgmul_k(unsigned short* __restrict__ z,
                                               const float* __restrict__ mu3, const float* __restrict__ rs3,
                                               const float* __restrict__ sgn_g, const float* __restrict__ sgn_b,
                                               const float* __restrict__ sg_w, const float* __restrict__ sg_b) {
    int tid = blockIdx.x * 256 + threadIdx.x;
    if (tid >= B_ * 384 * NPIX) return;
    int n = tid & (NPIX - 1);
    int bc = tid >> 14;
    int ch = bc % 384, b = bc / 384;
    int y = n >> 7, xx = n & 127;
    const unsigned short* zb = z + ((size_t)(b * 768 + 384 + ch) << 14);
    unsigned short* z1p = z + ((size_t)(b * 768 + ch) << 14);
    const float* mub = mu3 + (b << 14);
    const float* rsb = rs3 + (b << 14);
    float g = sgn_g[ch], bb = sgn_b[ch];
    float acc = sg_b[ch];
    #pragma unroll
    for (int dy = 0; dy < 3; ++dy) {
        int yy = y + dy - 1;
        if ((unsigned)yy >= 128u) continue;
        #pragma unroll
        for (int dx = 0; dx < 3; ++dx) {
            int xw = xx + dx - 1;
            if ((unsigned)xw >= 128u) continue;
            int nn = (yy << 7) + xw;
            float val = (bf2f(zb[nn]) - mub[nn]) * rsb[nn] * g + bb;
            acc += sg_w[ch * 9 + dy * 3 + dx] * val;
        }
    }
    z1p[n] = f2bf(bf2f(z1p[n]) * acc);
}

// ============================================================
extern "C" void kernel_launch(void* const* d_in, const int* in_sizes, int n_in,
                              void* d_out, int out_size, void* d_ws, size_t ws_size,
                              hipStream_t stream) {
    const float* x     = (const float*)d_in[0];
    const float* n1g   = (const float*)d_in[1];
    const float* n1b   = (const float*)d_in[2];
    const float* qkv_w = (const float*)d_in[3];
    const float* qkv_b = (const float*)d_in[4];
    const float* temp  = (const float*)d_in[5];
    const float* rpb   = (const float*)d_in[6];
    const float* proj_w= (const float*)d_in[7];
    const float* proj_b= (const float*)d_in[8];
    const float* hft_w = (const float*)d_in[9];
    const float* hft_b = (const float*)d_in[10];
    const float* n2g   = (const float*)d_in[11];
    const float* n2b   = (const float*)d_in[12];
    const float* fc1_w = (const float*)d_in[13];
    const float* fc1_b = (const float*)d_in[14];
    const float* sgn_g = (const float*)d_in[15];
    const float* sgn_b = (const float*)d_in[16];
    const float* sg_w  = (const float*)d_in[17];
    const float* sg_b  = (const float*)d_in[18];
    const float* fc2_w = (const float*)d_in[19];
    const float* fc2_b = (const float*)d_in[20];
    float* out = (float*)d_out;
    float* w = (float*)d_ws;

    // ---- workspace layout (float offsets; bf16 buffers cast) ----
    float* mu1 = w;            float* rs1 = w + 65536;
    float* mu2 = w + 131072;   float* rs2 = w + 196608;
    float* mu3 = w + 262144;   float* rs3 = w + 327680;
    unsigned short* wgb_qkv = (unsigned short*)(w + 393216);   // 576*192 bf16
    float* wsum_qkv = w + 448512;  float* wb_qkv = w + 449088;
    unsigned short* wgb_fc1 = (unsigned short*)(w + 449664);   // 768*192 bf16
    float* wsum_fc1 = w + 523392;  float* wb_fc1 = w + 524160;
    unsigned short* pwb  = (unsigned short*)(w + 524928);      // 192*192 bf16
    unsigned short* f2wb = (unsigned short*)(w + 543360);      // 192*384 bf16
    // R1: xt / attn_t (bf16 4*16384*192 = 6291456 f)
    unsigned short* xt     = (unsigned short*)(w + 580224);
    unsigned short* attn_t = xt;
    // R2 (18874368 f): qkv_b -> proj_out/p2/p4/p8 -> x1t -> z1t
    unsigned short* qkvb = (unsigned short*)(w + 6871680);     // bf16 4*576*16384
    float* proj_out = w + 6871680;                             // fp32 12582912
    float* p2 = w + 19454592;  float* p4 = w + 22600320;  float* p8 = w + 23386752;
    unsigned short* x1t  = (unsigned short*)(w + 6871680);     // bf16 4*16384*192
    unsigned short* z1t  = (unsigned short*)(w + 6871680);     // bf16 4*16384*384
    // R3 (25165824 f): o_win/s_win/s_img -> abuf -> z
    float* o_win = w + 25746048;                               // 23789568
    float* s_win = w + 49535616;                               // 743424
    float* s_img = w + 50279040;                               // 393216
    float* abuf  = w + 25746048;                               // 12582912
    unsigned short* z = (unsigned short*)(w + 25746048);       // bf16 4*768*16384 = 25165824 f
    // R4: x1 persists
    float* x1 = w + 50911872;                                  // 12582912; end 63494784

    // ---- stage A: transpose x, LN1, prep, qkv GEMM (bf16 out) ----
    transpose_k<float><<<dim3(256, 3, B_), 256, 0, stream>>>(x, xt, 192, 192 * NPIX);
    ln_stats_k<float><<<256, 256, 0, stream>>>(x, 192, 192 * NPIX, mu1, rs1);
    prep_k<<<3, 256, 0, stream>>>(qkv_w, n1g, n1b, qkv_b, 576, 192, wgb_qkv, wsum_qkv, wb_qkv);
    gemm_mfma_k<192, 128, 0, true, false, true><<<dim3(512, 9), 256, 0, stream>>>(
        wgb_qkv, xt, qkvb, mu1, rs1, wsum_qkv, wb_qkv, nullptr, 576);
    // ---- stage B: window attention ----
    attn_k<<<NWIN * HEADS, 256, 0, stream>>>(qkvb, rpb, temp, o_win, s_win);
    // ---- stage C: fold (writes attn_t bf16 [n][c]) ----
    simg_k<<<1536, 256, 0, stream>>>(s_win, s_img);
    fold_k<<<6144, 256, 0, stream>>>(o_win, s_img, attn_t);
    // ---- stage D: proj GEMM (fp32 out) ----
    wcvt_k<<<144, 256, 0, stream>>>(proj_w, pwb, 192 * 192);
    gemm_mfma_k<192, 128, 0, false, false, false><<<dim3(512, 3), 256, 0, stream>>>(
        pwb, attn_t, proj_out, nullptr, nullptr, nullptr, proj_b, nullptr, 192);
    // ---- stage E: HFT + residual -> x1 ----
    halve_k<<<12288, 256, 0, stream>>>(proj_out, p2, 128);
    halve_k<<<3072, 256, 0, stream>>>(p2, p4, 64);
    halve_k<<<768, 256, 0, stream>>>(p4, p8, 32);
    hfa_k<<<49152, 256, 0, stream>>>(proj_out, p2, p4, p8, abuf);
    hft_k<<<49152, 256, 0, stream>>>(abuf, proj_out, x, hft_w, hft_b, x1);
    // ---- stage F: LN2 + fc1 GEMM (GELU, bf16 out z[768]) ----
    transpose_k<float><<<dim3(256, 3, B_), 256, 0, stream>>>(x1, x1t, 192, 192 * NPIX);
    ln_stats_k<float><<<256, 256, 0, stream>>>(x1, 192, 192 * NPIX, mu2, rs2);
    prep_k<<<3, 256, 0, stream>>>(fc1_w, n2g, n2b, fc1_b, 768, 192, wgb_fc1, wsum_fc1, wb_fc1);
    gemm_mfma_k<192, 128, 1, true, false, true><<<dim3(512, 12), 256, 0, stream>>>(
        wgb_fc1, x1t, z, mu2, rs2, wsum_fc1, wb_fc1, nullptr, 768);
    // ---- stage G: SimpleGate (in-place on z1 rows) ----
    ln_stats_k<unsigned short><<<256, 256, 0, stream>>>(z + (size_t)384 * NPIX, 384, 768 * NPIX, mu3, rs3);
    sgmul_k<<<98304, 256, 0, stream>>>(z, mu3, rs3, sgn_g, sgn_b, sg_w, sg_b);
    // ---- stage H: transpose z1, fc2 GEMM + residual -> out ----
    transpose_k<unsigned short><<<dim3(256, 6, B_), 256, 0, stream>>>(z, z1t, 384, 768 * NPIX);
    wcvt_k<<<288, 256, 0, stream>>>(fc2_w, f2wb, 192 * 384);
    gemm_mfma_k<384, 64, 0, false, true, false><<<dim3(1024, 3), 256, 0, stream>>>(
        f2wb, z1t, out, nullptr, nullptr, nullptr, fc2_b, x1, 192);
}

// Round 4
// 1038.668 us; speedup vs baseline: 1.7222x; 1.1743x over previous
//
#include <hip/hip_runtime.h>
#include <math.h>

// ---- problem constants ----
static constexpr int B_    = 4;
static constexpr int C_    = 192;
static constexpr int NPIX  = 16384;            // 128*128
static constexpr int PTOT  = B_ * NPIX;        // 65536
static constexpr int HEADS = 6;
static constexpr int STR   = 6;
static constexpr int LH    = 22;
static constexpr int LWIN  = LH * LH;          // 484
static constexpr int NWIN  = B_ * LWIN;        // 1936

typedef short bf16x8 __attribute__((ext_vector_type(8)));
typedef float f32x4  __attribute__((ext_vector_type(4)));

__device__ __forceinline__ unsigned short f2bf(float f) {
    union { float f; unsigned int u; } v; v.f = f;
    unsigned int r = v.u + 0x7FFFu + ((v.u >> 16) & 1u);
    return (unsigned short)(r >> 16);
}
__device__ __forceinline__ float bf2f(unsigned short h) {
    union { unsigned int u; float f; } v; v.u = ((unsigned int)h) << 16;
    return v.f;
}

// ============================================================
// LN stats per pixel over Cn channels. in layout [b][*][NPIX],
// image stride bstride elements, channel rows contiguous NPIX.
// ============================================================
template <typename T>
__global__ __launch_bounds__(256) void ln_stats_k(const T* __restrict__ in, int Cn, int bstride,
                                                  float* __restrict__ mu, float* __restrict__ rs) {
    int p = blockIdx.x * 256 + threadIdx.x;
    if (p >= PTOT) return;
    int b = p >> 14, n = p & (NPIX - 1);
    const T* base = in + (size_t)b * bstride + n;
    float s = 0.f, s2 = 0.f;
    for (int c = 0; c < Cn; ++c) {
        float v;
        if constexpr (sizeof(T) == 2) v = bf2f(base[(size_t)c * NPIX]);
        else                          v = base[(size_t)c * NPIX];
        s += v; s2 += v * v;
    }
    float m = s / Cn;
    float var = s2 / Cn - m * m;
    mu[p] = m;
    rs[p] = rsqrtf(var + 1e-5f);
}

// ============================================================
// prep: wgb = bf16(W*g); wsum = sum(W*g); wb = W·bln + bias
// ============================================================
__global__ __launch_bounds__(256) void prep_k(const float* __restrict__ W, const float* __restrict__ g,
                                              const float* __restrict__ bln, const float* __restrict__ bias,
                                              int M, int K,
                                              unsigned short* __restrict__ wgb, float* __restrict__ wsum,
                                              float* __restrict__ wb) {
    int o = blockIdx.x * 256 + threadIdx.x;
    if (o >= M) return;
    float sum = 0.f, bb = 0.f;
    for (int c = 0; c < K; ++c) {
        float wv = W[(size_t)o * K + c];
        float wgv = wv * g[c];
        wgb[(size_t)o * K + c] = f2bf(wgv);
        sum += wgv;
        bb += wv * bln[c];
    }
    wsum[o] = sum;
    wb[o] = bb + bias[o];
}

// plain fp32 -> bf16 convert
__global__ __launch_bounds__(256) void wcvt_k(const float* __restrict__ W, unsigned short* __restrict__ Wb, int n) {
    int i = blockIdx.x * 256 + threadIdx.x;
    if (i < n) Wb[i] = f2bf(W[i]);
}

// ============================================================
// transpose-convert: [Cn][NPIX] (T) -> [NPIX][Cn] bf16, per image
// ============================================================
template <typename T>
__global__ __launch_bounds__(256) void transpose_k(const T* __restrict__ in, unsigned short* __restrict__ out,
                                                   int Cn, int bstride) {
    __shared__ float tile[64][65];
    int n0 = blockIdx.x << 6, c0 = blockIdx.y << 6, b = blockIdx.z;
    int t = threadIdx.x, r = t >> 2, cg = (t & 3) << 4;
    const T* ib = in + (size_t)b * bstride;
    if constexpr (sizeof(T) == 4) {
        const float4* src = (const float4*)(ib + (size_t)(c0 + r) * NPIX + n0 + cg);
        #pragma unroll
        for (int j = 0; j < 4; ++j) {
            float4 v = src[j];
            tile[r][cg + 4 * j + 0] = v.x; tile[r][cg + 4 * j + 1] = v.y;
            tile[r][cg + 4 * j + 2] = v.z; tile[r][cg + 4 * j + 3] = v.w;
        }
    } else {
        const uint4* src = (const uint4*)((const unsigned short*)ib + (size_t)(c0 + r) * NPIX + n0 + cg);
        uint4 v0 = src[0], v1 = src[1];
        unsigned int arr[8] = {v0.x, v0.y, v0.z, v0.w, v1.x, v1.y, v1.z, v1.w};
        #pragma unroll
        for (int j = 0; j < 8; ++j) {
            tile[r][cg + 2 * j]     = bf2f((unsigned short)(arr[j] & 0xFFFFu));
            tile[r][cg + 2 * j + 1] = bf2f((unsigned short)(arr[j] >> 16));
        }
    }
    __syncthreads();
    unsigned int pk[8];
    #pragma unroll
    for (int j = 0; j < 8; ++j) {
        unsigned int lo = f2bf(tile[cg + 2 * j][r]);
        unsigned int hi = f2bf(tile[cg + 2 * j + 1][r]);
        pk[j] = lo | (hi << 16);
    }
    uint4* dst = (uint4*)(out + ((size_t)(b << 14) + n0 + r) * Cn + c0 + cg);
    dst[0] = make_uint4(pk[0], pk[1], pk[2], pk[3]);
    dst[1] = make_uint4(pk[4], pk[5], pk[6], pk[7]);
}

// ============================================================
// MFMA GEMM (unchanged from round 3)
// ============================================================
template <int KK, int PIXT, int ACT, bool LN, bool RES, bool OBF>
__global__ __launch_bounds__(256) void gemm_mfma_k(const unsigned short* __restrict__ Wb,
                                                   const unsigned short* __restrict__ Xt,
                                                   void* __restrict__ outv,
                                                   const float* __restrict__ mu, const float* __restrict__ rs,
                                                   const float* __restrict__ wsum, const float* __restrict__ wb,
                                                   const float* __restrict__ resid, int M) {
    constexpr int LDK    = KK + 8;
    constexpr int KSTEPS = KK / 32;
    constexpr int MREP   = PIXT / 32;
    constexpr int NREP   = 2;
    __shared__ unsigned short xs[PIXT * LDK];

    int t = threadIdx.x;
    int gp = blockIdx.x * PIXT;
    int b  = gp >> 14;
    int n0 = gp & (NPIX - 1);
    int o0 = blockIdx.y << 6;

    const unsigned short* xg = Xt + (size_t)(b * NPIX + n0) * KK;
    constexpr int NJ = KK / 8;
    #pragma unroll
    for (int i = 0; i < PIXT * NJ / 256; ++i) {
        int c = i * 256 + t;
        int p, j;
        if (KK == 192) { p = (c * 2731) >> 16; j = c - p * 24; }
        else           { int q = c >> 4; p = (q * 21846) >> 16; j = c - p * 48; }
        uint4 v = *(const uint4*)(xg + (size_t)p * KK + j * 8);
        *(uint4*)&xs[p * LDK + j * 8] = v;
    }
    __syncthreads();

    int w  = t >> 6, l = t & 63;
    int wr = w >> 1, wc = w & 1;
    int lr = l & 15, kb = l >> 4;
    int pw = wr * (PIXT / 2);
    int ow = o0 + wc * 32;

    f32x4 acc[MREP][NREP];
    #pragma unroll
    for (int m = 0; m < MREP; ++m)
        #pragma unroll
        for (int n = 0; n < NREP; ++n) acc[m][n] = (f32x4){0.f, 0.f, 0.f, 0.f};

    #pragma unroll
    for (int ks = 0; ks < KSTEPS; ++ks) {
        int k0 = ks * 32;
        bf16x8 bfr[NREP];
        #pragma unroll
        for (int n = 0; n < NREP; ++n) {
            int o = ow + n * 16 + lr;
            bfr[n] = *(const bf16x8*)(Wb + (size_t)o * KK + k0 + kb * 8);
        }
        bf16x8 afr[MREP];
        #pragma unroll
        for (int m = 0; m < MREP; ++m) {
            int p = pw + m * 16 + lr;
            afr[m] = *(const bf16x8*)&xs[p * LDK + k0 + kb * 8];
        }
        #pragma unroll
        for (int m = 0; m < MREP; ++m)
            #pragma unroll
            for (int n = 0; n < NREP; ++n)
                acc[m][n] = __builtin_amdgcn_mfma_f32_16x16x32_bf16(afr[m], bfr[n], acc[m][n], 0, 0, 0);
    }

    #pragma unroll
    for (int m = 0; m < MREP; ++m) {
        int prow = pw + m * 16 + kb * 4;
        int nidx = n0 + prow;
        float muv[4], rsv[4];
        if (LN) {
            #pragma unroll
            for (int r = 0; r < 4; ++r) {
                muv[r] = mu[(b << 14) + nidx + r];
                rsv[r] = rs[(b << 14) + nidx + r];
            }
        }
        #pragma unroll
        for (int n = 0; n < NREP; ++n) {
            int o = ow + n * 16 + lr;
            float wbv = wb[o];
            float wsv = 0.f; if (LN) wsv = wsum[o];
            size_t obase = (((size_t)b * M + o) << 14) + nidx;
            float rv[4] = {0.f, 0.f, 0.f, 0.f};
            if (RES) {
                float4 rr = *(const float4*)(resid + obase);
                rv[0] = rr.x; rv[1] = rr.y; rv[2] = rr.z; rv[3] = rr.w;
            }
            float vo[4];
            #pragma unroll
            for (int r = 0; r < 4; ++r) {
                float a = acc[m][n][r];
                float v = LN ? (rsv[r] * a - muv[r] * rsv[r] * wsv + wbv) : (a + wbv);
                if (ACT == 1) v = 0.5f * v * (1.f + erff(v * 0.70710678118654752f));
                vo[r] = v + rv[r];
            }
            if (OBF) {
                ushort4 u;
                u.x = f2bf(vo[0]); u.y = f2bf(vo[1]); u.z = f2bf(vo[2]); u.w = f2bf(vo[3]);
                *(ushort4*)((unsigned short*)outv + obase) = u;
            } else {
                float4 f = {vo[0], vo[1], vo[2], vo[3]};
                *(float4*)((float*)outv + obase) = f;
            }
        }
    }
}

// ============================================================
// MFMA attention: ONE WAVE per (window, head).
// S^T = K·Q^T via mfma(A=K, B=Q^T): D[j][i], col i = lane&15.
// Softmax over j = in-register (16 vals) + shfl_xor(16,32).
// P through padded LDS; O = P·V via mfma(A=P, B=V).
// qkv bf16 [b][576][NPIX]; q:0-191, k:192-383, v:384-575.
// ============================================================
__global__ __launch_bounds__(64) void attn_mfma_k(const unsigned short* __restrict__ qkv,
                                                  const float* __restrict__ rpb,
                                                  const float* __restrict__ temp,
                                                  float* __restrict__ o_win, float* __restrict__ s_win) {
    __shared__ unsigned short p_lds[64 * 72];   // [i][j], row stride 72 halfs (144B, 16B-aligned)
    __shared__ float rp[225];
    int wh = blockIdx.x;
    int head = wh % HEADS;
    int bw = wh / HEADS;
    int b = bw / LWIN, l = bw % LWIN;
    int sh = l / LH, sw = l % LH;
    int h0 = sh * STR - 3, w0 = sw * STR - 3;
    int t = threadIdx.x;             // 0..63
    int lr = t & 15, kb = t >> 4;

    for (int i = t; i < 225; i += 64) rp[i] = rpb[i * HEADS + head];
    float tmp = temp[head];

    const size_t qbase = ((size_t)(b * 576 + head * 32)) << 14;
    const unsigned short* qp = qkv + qbase;
    const unsigned short* kp = qkv + qbase + ((size_t)192 << 14);
    const unsigned short* vp = qkv + qbase + ((size_t)384 << 14);

    // ---- K A-frags: lane -> K[16m+lr][kb*8+j] ; Q B-frags: Q[16n+lr][kb*8+j] ----
    bf16x8 kf[4], qf[4];
    #pragma unroll
    for (int m = 0; m < 4; ++m) {
        int jp = m * 16 + lr;
        int hh = h0 + (jp >> 3), ww = w0 + (jp & 7);
        bool ok = ((unsigned)hh < 128u) && ((unsigned)ww < 128u);
        int pix = (hh << 7) + ww;
        #pragma unroll
        for (int j = 0; j < 8; ++j) {
            unsigned short kv = 0, qv = 0;
            if (ok) {
                size_t off = ((size_t)(kb * 8 + j) << 14) + pix;
                kv = kp[off];
                qv = qp[off];
            }
            kf[m][j] = (short)kv;
            qf[m][j] = (short)qv;
        }
    }

    // ---- QK^T -> S^T fragments st[m(j-blk)][n(i-blk)] ----
    f32x4 st[4][4];
    #pragma unroll
    for (int m = 0; m < 4; ++m)
        #pragma unroll
        for (int n = 0; n < 4; ++n) st[m][n] = (f32x4){0.f, 0.f, 0.f, 0.f};
    #pragma unroll
    for (int m = 0; m < 4; ++m)
        #pragma unroll
        for (int n = 0; n < 4; ++n)
            st[m][n] = __builtin_amdgcn_mfma_f32_16x16x32_bf16(kf[m], qf[n], st[m][n], 0, 0, 0);

    // ---- V B-frags (issue early; latency hides under softmax) ----
    // vf[n'][ks]: lane -> V[j = ks*32+kb*8+jj][c = n'*16+lr]
    bf16x8 vf[2][2];
    #pragma unroll
    for (int np = 0; np < 2; ++np) {
        #pragma unroll
        for (int ks = 0; ks < 2; ++ks) {
            int hh = h0 + ks * 4 + kb;
            bool okr = (unsigned)hh < 128u;
            const unsigned short* vrow = vp + (((size_t)(np * 16 + lr)) << 14) + (hh << 7) + w0;
            #pragma unroll
            for (int j = 0; j < 8; ++j) {
                int ww = w0 + j;
                unsigned short vv = 0;
                if (okr && (unsigned)ww < 128u) vv = vrow[j];
                vf[np][ks][j] = (short)vv;
            }
        }
    }

    __syncthreads();   // rp staging visible

    // ---- scale + bias ----
    #pragma unroll
    for (int n = 0; n < 4; ++n) {
        int i = n * 16 + lr;
        int iyy = i >> 3, ixx = i & 7;
        #pragma unroll
        for (int m = 0; m < 4; ++m) {
            #pragma unroll
            for (int r = 0; r < 4; ++r) {
                int j = m * 16 + kb * 4 + r;
                int dy = iyy - (j >> 3) + 7;
                int dx = ixx - (j & 7) + 7;
                st[m][n][r] = st[m][n][r] * tmp + rp[dy * 15 + dx];
            }
        }
    }

    // ---- softmax over j per column i; write P (bf16) to LDS; store s ----
    #pragma unroll
    for (int n = 0; n < 4; ++n) {
        float mx = -1e30f;
        #pragma unroll
        for (int m = 0; m < 4; ++m)
            #pragma unroll
            for (int r = 0; r < 4; ++r) mx = fmaxf(mx, st[m][n][r]);
        mx = fmaxf(mx, __shfl_xor(mx, 16));
        mx = fmaxf(mx, __shfl_xor(mx, 32));
        float s = 0.f;
        #pragma unroll
        for (int m = 0; m < 4; ++m) {
            #pragma unroll
            for (int r = 0; r < 4; ++r) {
                float e = __expf(st[m][n][r] - mx);
                st[m][n][r] = e;
                s += e;
            }
        }
        s += __shfl_xor(s, 16);
        s += __shfl_xor(s, 32);
        int i = n * 16 + lr;
        if (kb == 0) s_win[(size_t)wh * 64 + i] = s;
        #pragma unroll
        for (int m = 0; m < 4; ++m) {
            unsigned int lo = (unsigned int)f2bf(st[m][n][0]) | ((unsigned int)f2bf(st[m][n][1]) << 16);
            unsigned int hi = (unsigned int)f2bf(st[m][n][2]) | ((unsigned int)f2bf(st[m][n][3]) << 16);
            *(unsigned int*)&p_lds[i * 72 + m * 16 + kb * 4]     = lo;
            *(unsigned int*)&p_lds[i * 72 + m * 16 + kb * 4 + 2] = hi;
        }
    }

    __syncthreads();   // P visible

    // ---- O = P·V ----
    f32x4 oc[4][2];
    #pragma unroll
    for (int m = 0; m < 4; ++m)
        #pragma unroll
        for (int np = 0; np < 2; ++np) oc[m][np] = (f32x4){0.f, 0.f, 0.f, 0.f};
    #pragma unroll
    for (int ks = 0; ks < 2; ++ks) {
        bf16x8 pa[4];
        #pragma unroll
        for (int m = 0; m < 4; ++m)
            pa[m] = *(const bf16x8*)&p_lds[(m * 16 + lr) * 72 + ks * 32 + kb * 8];
        #pragma unroll
        for (int m = 0; m < 4; ++m)
            #pragma unroll
            for (int np = 0; np < 2; ++np)
                oc[m][np] = __builtin_amdgcn_mfma_f32_16x16x32_bf16(pa[m], vf[np][ks], oc[m][np], 0, 0, 0);
    }

    // ---- store O: o_win[wh][i][c], i = 16m+4kb+r, c = 16n'+lr ----
    float* ob = o_win + (size_t)wh * 2048;
    #pragma unroll
    for (int m = 0; m < 4; ++m) {
        int ibase = m * 16 + kb * 4;
        #pragma unroll
        for (int np = 0; np < 2; ++np) {
            int c = np * 16 + lr;
            #pragma unroll
            for (int r = 0; r < 4; ++r)
                ob[(ibase + r) * 32 + c] = oc[m][np][r];
        }
    }
}

// ============================================================
__device__ __forceinline__ void win_range(int h, int& s0, int& s1) {
    s0 = (h + 1) / 6; if (s0 < 0) s0 = 0;
    s1 = (h + 3) / 6; if (s1 > 21) s1 = 21;
}

__global__ __launch_bounds__(256) void simg_k(const float* __restrict__ s_win, float* __restrict__ s_img) {
    int tid = blockIdx.x * 256 + threadIdx.x;
    if (tid >= B_ * HEADS * NPIX) return;
    int n = tid & (NPIX - 1);
    int bh = tid >> 14;
    int hd = bh % HEADS, b = bh / HEADS;
    int hy = n >> 7, wx = n & 127;
    int sy0, sy1, sx0, sx1;
    win_range(hy, sy0, sy1);
    win_range(wx, sx0, sx1);
    float acc = 0.f;
    for (int sy = sy0; sy <= sy1; ++sy)
        for (int sx = sx0; sx <= sx1; ++sx) {
            int idx = (hy - (sy * 6 - 3)) * 8 + (wx - (sx * 6 - 3));
            acc += s_win[(size_t)((b * LWIN + sy * LH + sx) * HEADS + hd) * 64 + idx];
        }
    s_img[tid] = acc;
}

// ============================================================
// fold o + divide -> attn_t bf16 [b][n][192]
// ============================================================
__global__ __launch_bounds__(256) void fold_k(const float* __restrict__ o_win, const float* __restrict__ s_img,
                                              unsigned short* __restrict__ attn_t) {
    int tid = blockIdx.x * 256 + threadIdx.x;   // < 4*16384*24
    int q = (int)((((unsigned long long)(tid >> 3)) * 174763ull) >> 19);  // tid/24
    int oct = tid - q * 24;
    int n = q & (NPIX - 1), b = q >> 14;
    int hd = oct >> 2, c8 = (oct & 3) << 3;
    int hy = n >> 7, wx = n & 127;
    int sy0, sy1, sx0, sx1;
    win_range(hy, sy0, sy1);
    win_range(wx, sx0, sx1);
    float acc[8] = {0.f, 0.f, 0.f, 0.f, 0.f, 0.f, 0.f, 0.f};
    for (int sy = sy0; sy <= sy1; ++sy)
        for (int sx = sx0; sx <= sx1; ++sx) {
            int idx = (hy - (sy * 6 - 3)) * 8 + (wx - (sx * 6 - 3));
            const float* p = o_win + ((size_t)((b * LWIN + sy * LH + sx) * HEADS + hd) * 2048 + idx * 32 + c8);
            float4 a0 = *(const float4*)p;
            float4 a1 = *(const float4*)(p + 4);
            acc[0] += a0.x; acc[1] += a0.y; acc[2] += a0.z; acc[3] += a0.w;
            acc[4] += a1.x; acc[5] += a1.y; acc[6] += a1.z; acc[7] += a1.w;
        }
    float inv = 1.f / s_img[((b * HEADS + hd) << 14) + n];
    unsigned int pk[4];
    #pragma unroll
    for (int j = 0; j < 4; ++j) {
        unsigned int lo = f2bf(acc[2 * j] * inv);
        unsigned int hi = f2bf(acc[2 * j + 1] * inv);
        pk[j] = lo | (hi << 16);
    }
    *(uint4*)&attn_t[((size_t)((b << 14) + n)) * 192 + hd * 32 + c8] = make_uint4(pk[0], pk[1], pk[2], pk[3]);
}

// ============================================================
// HFT chain (proj_out fp32 [b][192][NPIX])
// ============================================================
__global__ __launch_bounds__(256) void halve_k(const float* __restrict__ in, float* __restrict__ out, int Win) {
    int Wo = Win >> 1;
    int tot = B_ * C_ * Wo * Wo;
    int tid = blockIdx.x * 256 + threadIdx.x;
    if (tid >= tot) return;
    int xy = tid % (Wo * Wo);
    int bc = tid / (Wo * Wo);
    int y = xy / Wo, x = xy % Wo;
    const float* p = in + (size_t)bc * Win * Win + (size_t)(2 * y) * Win + 2 * x;
    out[tid] = 0.25f * (p[0] + p[1] + p[Win] + p[Win + 1]);
}

__global__ __launch_bounds__(256) void hfa_k(const float* __restrict__ po, const float* __restrict__ p2,
                                             const float* __restrict__ p4, const float* __restrict__ p8,
                                             float* __restrict__ a) {
    int tid = blockIdx.x * 256 + threadIdx.x;
    if (tid >= B_ * C_ * NPIX) return;
    int n = tid & (NPIX - 1);
    int bc = tid >> 14;
    int y = n >> 7, x = n & 127;
    float v = 3.f * po[tid]
            - p2[((size_t)bc << 12) + ((y >> 1) << 6) + (x >> 1)]
            - p4[((size_t)bc << 10) + ((y >> 2) << 5) + (x >> 2)]
            - p8[((size_t)bc << 8)  + ((y >> 3) << 4) + (x >> 3)];
    a[tid] = v;
}

__global__ __launch_bounds__(256) void hft_k(const float* __restrict__ a, const float* __restrict__ po,
                                             const float* __restrict__ x, const float* __restrict__ hw,
                                             const float* __restrict__ hb, float* __restrict__ x1) {
    int tid = blockIdx.x * 256 + threadIdx.x;
    if (tid >= B_ * C_ * NPIX) return;
    int n = tid & (NPIX - 1);
    int bc = tid >> 14;
    int ch = bc % C_;
    int y = n >> 7, xx = n & 127;
    const float* ab = a + ((size_t)bc << 14);
    float acc = hb[ch];
    #pragma unroll
    for (int dy = 0; dy < 3; ++dy) {
        int yy = y + dy - 1;
        if ((unsigned)yy >= 128u) continue;
        #pragma unroll
        for (int dx = 0; dx < 3; ++dx) {
            int xw = xx + dx - 1;
            if ((unsigned)xw >= 128u) continue;
            acc += hw[ch * 9 + dy * 3 + dx] * ab[(yy << 7) + xw];
        }
    }
    float sg = 1.f / (1.f + expf(-acc));
    x1[tid] = x[tid] + sg * po[tid];
}

// ============================================================
// SimpleGate on bf16 z: z1 *= dwconv3(LN(z2));  z = [b][768][NPIX] bf16
// ============================================================
__global__ __launch_bounds__(256) void sgmul_k(unsigned short* __restrict__ z,
                                               const float* __restrict__ mu3, const float* __restrict__ rs3,
                                               const float* __restrict__ sgn_g, const float* __restrict__ sgn_b,
                                               const float* __restrict__ sg_w, const float* __restrict__ sg_b) {
    int tid = blockIdx.x * 256 + threadIdx.x;
    if (tid >= B_ * 384 * NPIX) return;
    int n = tid & (NPIX - 1);
    int bc = tid >> 14;
    int ch = bc % 384, b = bc / 384;
    int y = n >> 7, xx = n & 127;
    const unsigned short* zb = z + ((size_t)(b * 768 + 384 + ch) << 14);
    unsigned short* z1p = z + ((size_t)(b * 768 + ch) << 14);
    const float* mub = mu3 + (b << 14);
    const float* rsb = rs3 + (b << 14);
    float g = sgn_g[ch], bb = sgn_b[ch];
    float acc = sg_b[ch];
    #pragma unroll
    for (int dy = 0; dy < 3; ++dy) {
        int yy = y + dy - 1;
        if ((unsigned)yy >= 128u) continue;
        #pragma unroll
        for (int dx = 0; dx < 3; ++dx) {
            int xw = xx + dx - 1;
            if ((unsigned)xw >= 128u) continue;
            int nn = (yy << 7) + xw;
            float val = (bf2f(zb[nn]) - mub[nn]) * rsb[nn] * g + bb;
            acc += sg_w[ch * 9 + dy * 3 + dx] * val;
        }
    }
    z1p[n] = f2bf(bf2f(z1p[n]) * acc);
}

// ============================================================
extern "C" void kernel_launch(void* const* d_in, const int* in_sizes, int n_in,
                              void* d_out, int out_size, void* d_ws, size_t ws_size,
                              hipStream_t stream) {
    const float* x     = (const float*)d_in[0];
    const float* n1g   = (const float*)d_in[1];
    const float* n1b   = (const float*)d_in[2];
    const float* qkv_w = (const float*)d_in[3];
    const float* qkv_b = (const float*)d_in[4];
    const float* temp  = (const float*)d_in[5];
    const float* rpb   = (const float*)d_in[6];
    const float* proj_w= (const float*)d_in[7];
    const float* proj_b= (const float*)d_in[8];
    const float* hft_w = (const float*)d_in[9];
    const float* hft_b = (const float*)d_in[10];
    const float* n2g   = (const float*)d_in[11];
    const float* n2b   = (const float*)d_in[12];
    const float* fc1_w = (const float*)d_in[13];
    const float* fc1_b = (const float*)d_in[14];
    const float* sgn_g = (const float*)d_in[15];
    const float* sgn_b = (const float*)d_in[16];
    const float* sg_w  = (const float*)d_in[17];
    const float* sg_b  = (const float*)d_in[18];
    const float* fc2_w = (const float*)d_in[19];
    const float* fc2_b = (const float*)d_in[20];
    float* out = (float*)d_out;
    float* w = (float*)d_ws;

    // ---- workspace layout (float offsets; bf16 buffers cast) ----
    float* mu1 = w;            float* rs1 = w + 65536;
    float* mu2 = w + 131072;   float* rs2 = w + 196608;
    float* mu3 = w + 262144;   float* rs3 = w + 327680;
    unsigned short* wgb_qkv = (unsigned short*)(w + 393216);
    float* wsum_qkv = w + 448512;  float* wb_qkv = w + 449088;
    unsigned short* wgb_fc1 = (unsigned short*)(w + 449664);
    float* wsum_fc1 = w + 523392;  float* wb_fc1 = w + 524160;
    unsigned short* pwb  = (unsigned short*)(w + 524928);
    unsigned short* f2wb = (unsigned short*)(w + 543360);
    unsigned short* xt     = (unsigned short*)(w + 580224);
    unsigned short* attn_t = xt;
    unsigned short* qkvb = (unsigned short*)(w + 6871680);
    float* proj_out = w + 6871680;
    float* p2 = w + 19454592;  float* p4 = w + 22600320;  float* p8 = w + 23386752;
    unsigned short* x1t  = (unsigned short*)(w + 6871680);
    unsigned short* z1t  = (unsigned short*)(w + 6871680);
    float* o_win = w + 25746048;
    float* s_win = w + 49535616;
    float* s_img = w + 50279040;
    float* abuf  = w + 25746048;
    unsigned short* z = (unsigned short*)(w + 25746048);
    float* x1 = w + 50911872;

    // ---- stage A: transpose x, LN1, prep, qkv GEMM (bf16 out) ----
    transpose_k<float><<<dim3(256, 3, B_), 256, 0, stream>>>(x, xt, 192, 192 * NPIX);
    ln_stats_k<float><<<256, 256, 0, stream>>>(x, 192, 192 * NPIX, mu1, rs1);
    prep_k<<<3, 256, 0, stream>>>(qkv_w, n1g, n1b, qkv_b, 576, 192, wgb_qkv, wsum_qkv, wb_qkv);
    gemm_mfma_k<192, 128, 0, true, false, true><<<dim3(512, 9), 256, 0, stream>>>(
        wgb_qkv, xt, qkvb, mu1, rs1, wsum_qkv, wb_qkv, nullptr, 576);
    // ---- stage B: MFMA window attention (1 wave / window-head) ----
    attn_mfma_k<<<NWIN * HEADS, 64, 0, stream>>>(qkvb, rpb, temp, o_win, s_win);
    // ---- stage C: fold ----
    simg_k<<<1536, 256, 0, stream>>>(s_win, s_img);
    fold_k<<<6144, 256, 0, stream>>>(o_win, s_img, attn_t);
    // ---- stage D: proj GEMM (fp32 out) ----
    wcvt_k<<<144, 256, 0, stream>>>(proj_w, pwb, 192 * 192);
    gemm_mfma_k<192, 128, 0, false, false, false><<<dim3(512, 3), 256, 0, stream>>>(
        pwb, attn_t, proj_out, nullptr, nullptr, nullptr, proj_b, nullptr, 192);
    // ---- stage E: HFT + residual -> x1 ----
    halve_k<<<12288, 256, 0, stream>>>(proj_out, p2, 128);
    halve_k<<<3072, 256, 0, stream>>>(p2, p4, 64);
    halve_k<<<768, 256, 0, stream>>>(p4, p8, 32);
    hfa_k<<<49152, 256, 0, stream>>>(proj_out, p2, p4, p8, abuf);
    hft_k<<<49152, 256, 0, stream>>>(abuf, proj_out, x, hft_w, hft_b, x1);
    // ---- stage F: LN2 + fc1 GEMM (GELU, bf16 out z[768]) ----
    transpose_k<float><<<dim3(256, 3, B_), 256, 0, stream>>>(x1, x1t, 192, 192 * NPIX);
    ln_stats_k<float><<<256, 256, 0, stream>>>(x1, 192, 192 * NPIX, mu2, rs2);
    prep_k<<<3, 256, 0, stream>>>(fc1_w, n2g, n2b, fc1_b, 768, 192, wgb_fc1, wsum_fc1, wb_fc1);
    gemm_mfma_k<192, 128, 1, true, false, true><<<dim3(512, 12), 256, 0, stream>>>(
        wgb_fc1, x1t, z, mu2, rs2, wsum_fc1, wb_fc1, nullptr, 768);
    // ---- stage G: SimpleGate (in-place on z1 rows) ----
    ln_stats_k<unsigned short><<<256, 256, 0, stream>>>(z + (size_t)384 * NPIX, 384, 768 * NPIX, mu3, rs3);
    sgmul_k<<<98304, 256, 0, stream>>>(z, mu3, rs3, sgn_g, sgn_b, sg_w, sg_b);
    // ---- stage H: transpose z1, fc2 GEMM + residual -> out ----
    transpose_k<unsigned short><<<dim3(256, 6, B_), 256, 0, stream>>>(z, z1t, 384, 768 * NPIX);
    wcvt_k<<<288, 256, 0, stream>>>(fc2_w, f2wb, 192 * 384);
    gemm_mfma_k<384, 64, 0, false, true, false><<<dim3(1024, 3), 256, 0, stream>>>(
        f2wb, z1t, out, nullptr, nullptr, nullptr, fc2_b, x1, 192);
}

// Round 5
// 834.146 us; speedup vs baseline: 2.1445x; 1.2452x over previous
//
#include <hip/hip_runtime.h>
#include <math.h>

// ---- problem constants ----
static constexpr int B_    = 4;
static constexpr int C_    = 192;
static constexpr int NPIX  = 16384;            // 128*128
static constexpr int PTOT  = B_ * NPIX;        // 65536
static constexpr int HEADS = 6;
static constexpr int STR   = 6;
static constexpr int LH    = 22;
static constexpr int LWIN  = LH * LH;          // 484
static constexpr int NWIN  = B_ * LWIN;        // 1936

typedef short bf16x8 __attribute__((ext_vector_type(8)));
typedef float f32x4  __attribute__((ext_vector_type(4)));

__device__ __forceinline__ unsigned short f2bf(float f) {
    union { float f; unsigned int u; } v; v.f = f;
    unsigned int r = v.u + 0x7FFFu + ((v.u >> 16) & 1u);
    return (unsigned short)(r >> 16);
}
__device__ __forceinline__ float bf2f(unsigned short h) {
    union { unsigned int u; float f; } v; v.u = ((unsigned int)h) << 16;
    return v.f;
}

// ============================================================
// LN stats per pixel over Cn channels. in layout [b][*][NPIX],
// image stride bstride elements, channel rows contiguous NPIX.
// ============================================================
template <typename T>
__global__ __launch_bounds__(256) void ln_stats_k(const T* __restrict__ in, int Cn, int bstride,
                                                  float* __restrict__ mu, float* __restrict__ rs) {
    int p = blockIdx.x * 256 + threadIdx.x;
    if (p >= PTOT) return;
    int b = p >> 14, n = p & (NPIX - 1);
    const T* base = in + (size_t)b * bstride + n;
    float s = 0.f, s2 = 0.f;
    for (int c = 0; c < Cn; ++c) {
        float v;
        if constexpr (sizeof(T) == 2) v = bf2f(base[(size_t)c * NPIX]);
        else                          v = base[(size_t)c * NPIX];
        s += v; s2 += v * v;
    }
    float m = s / Cn;
    float var = s2 / Cn - m * m;
    mu[p] = m;
    rs[p] = rsqrtf(var + 1e-5f);
}

// ============================================================
// prep: wgb = bf16(W*g); wsum = sum(W*g); wb = W·bln + bias
// ============================================================
__global__ __launch_bounds__(256) void prep_k(const float* __restrict__ W, const float* __restrict__ g,
                                              const float* __restrict__ bln, const float* __restrict__ bias,
                                              int M, int K,
                                              unsigned short* __restrict__ wgb, float* __restrict__ wsum,
                                              float* __restrict__ wb) {
    int o = blockIdx.x * 256 + threadIdx.x;
    if (o >= M) return;
    float sum = 0.f, bb = 0.f;
    for (int c = 0; c < K; ++c) {
        float wv = W[(size_t)o * K + c];
        float wgv = wv * g[c];
        wgb[(size_t)o * K + c] = f2bf(wgv);
        sum += wgv;
        bb += wv * bln[c];
    }
    wsum[o] = sum;
    wb[o] = bb + bias[o];
}

// plain fp32 -> bf16 convert
__global__ __launch_bounds__(256) void wcvt_k(const float* __restrict__ W, unsigned short* __restrict__ Wb, int n) {
    int i = blockIdx.x * 256 + threadIdx.x;
    if (i < n) Wb[i] = f2bf(W[i]);
}

// ============================================================
// transpose-convert: [Cn][NPIX] (T) -> [NPIX][Cn] bf16, per image
// ============================================================
template <typename T>
__global__ __launch_bounds__(256) void transpose_k(const T* __restrict__ in, unsigned short* __restrict__ out,
                                                   int Cn, int bstride) {
    __shared__ float tile[64][65];
    int n0 = blockIdx.x << 6, c0 = blockIdx.y << 6, b = blockIdx.z;
    int t = threadIdx.x, r = t >> 2, cg = (t & 3) << 4;
    const T* ib = in + (size_t)b * bstride;
    if constexpr (sizeof(T) == 4) {
        const float4* src = (const float4*)(ib + (size_t)(c0 + r) * NPIX + n0 + cg);
        #pragma unroll
        for (int j = 0; j < 4; ++j) {
            float4 v = src[j];
            tile[r][cg + 4 * j + 0] = v.x; tile[r][cg + 4 * j + 1] = v.y;
            tile[r][cg + 4 * j + 2] = v.z; tile[r][cg + 4 * j + 3] = v.w;
        }
    } else {
        const uint4* src = (const uint4*)((const unsigned short*)ib + (size_t)(c0 + r) * NPIX + n0 + cg);
        uint4 v0 = src[0], v1 = src[1];
        unsigned int arr[8] = {v0.x, v0.y, v0.z, v0.w, v1.x, v1.y, v1.z, v1.w};
        #pragma unroll
        for (int j = 0; j < 8; ++j) {
            tile[r][cg + 2 * j]     = bf2f((unsigned short)(arr[j] & 0xFFFFu));
            tile[r][cg + 2 * j + 1] = bf2f((unsigned short)(arr[j] >> 16));
        }
    }
    __syncthreads();
    unsigned int pk[8];
    #pragma unroll
    for (int j = 0; j < 8; ++j) {
        unsigned int lo = f2bf(tile[cg + 2 * j][r]);
        unsigned int hi = f2bf(tile[cg + 2 * j + 1][r]);
        pk[j] = lo | (hi << 16);
    }
    uint4* dst = (uint4*)(out + ((size_t)(b << 14) + n0 + r) * Cn + c0 + cg);
    dst[0] = make_uint4(pk[0], pk[1], pk[2], pk[3]);
    dst[1] = make_uint4(pk[4], pk[5], pk[6], pk[7]);
}

// ============================================================
// MFMA GEMM (unchanged)
// ============================================================
template <int KK, int PIXT, int ACT, bool LN, bool RES, bool OBF>
__global__ __launch_bounds__(256) void gemm_mfma_k(const unsigned short* __restrict__ Wb,
                                                   const unsigned short* __restrict__ Xt,
                                                   void* __restrict__ outv,
                                                   const float* __restrict__ mu, const float* __restrict__ rs,
                                                   const float* __restrict__ wsum, const float* __restrict__ wb,
                                                   const float* __restrict__ resid, int M) {
    constexpr int LDK    = KK + 8;
    constexpr int KSTEPS = KK / 32;
    constexpr int MREP   = PIXT / 32;
    constexpr int NREP   = 2;
    __shared__ unsigned short xs[PIXT * LDK];

    int t = threadIdx.x;
    int gp = blockIdx.x * PIXT;
    int b  = gp >> 14;
    int n0 = gp & (NPIX - 1);
    int o0 = blockIdx.y << 6;

    const unsigned short* xg = Xt + (size_t)(b * NPIX + n0) * KK;
    constexpr int NJ = KK / 8;
    #pragma unroll
    for (int i = 0; i < PIXT * NJ / 256; ++i) {
        int c = i * 256 + t;
        int p, j;
        if (KK == 192) { p = (c * 2731) >> 16; j = c - p * 24; }
        else           { int q = c >> 4; p = (q * 21846) >> 16; j = c - p * 48; }
        uint4 v = *(const uint4*)(xg + (size_t)p * KK + j * 8);
        *(uint4*)&xs[p * LDK + j * 8] = v;
    }
    __syncthreads();

    int w  = t >> 6, l = t & 63;
    int wr = w >> 1, wc = w & 1;
    int lr = l & 15, kb = l >> 4;
    int pw = wr * (PIXT / 2);
    int ow = o0 + wc * 32;

    f32x4 acc[MREP][NREP];
    #pragma unroll
    for (int m = 0; m < MREP; ++m)
        #pragma unroll
        for (int n = 0; n < NREP; ++n) acc[m][n] = (f32x4){0.f, 0.f, 0.f, 0.f};

    #pragma unroll
    for (int ks = 0; ks < KSTEPS; ++ks) {
        int k0 = ks * 32;
        bf16x8 bfr[NREP];
        #pragma unroll
        for (int n = 0; n < NREP; ++n) {
            int o = ow + n * 16 + lr;
            bfr[n] = *(const bf16x8*)(Wb + (size_t)o * KK + k0 + kb * 8);
        }
        bf16x8 afr[MREP];
        #pragma unroll
        for (int m = 0; m < MREP; ++m) {
            int p = pw + m * 16 + lr;
            afr[m] = *(const bf16x8*)&xs[p * LDK + k0 + kb * 8];
        }
        #pragma unroll
        for (int m = 0; m < MREP; ++m)
            #pragma unroll
            for (int n = 0; n < NREP; ++n)
                acc[m][n] = __builtin_amdgcn_mfma_f32_16x16x32_bf16(afr[m], bfr[n], acc[m][n], 0, 0, 0);
    }

    #pragma unroll
    for (int m = 0; m < MREP; ++m) {
        int prow = pw + m * 16 + kb * 4;
        int nidx = n0 + prow;
        float muv[4], rsv[4];
        if (LN) {
            #pragma unroll
            for (int r = 0; r < 4; ++r) {
                muv[r] = mu[(b << 14) + nidx + r];
                rsv[r] = rs[(b << 14) + nidx + r];
            }
        }
        #pragma unroll
        for (int n = 0; n < NREP; ++n) {
            int o = ow + n * 16 + lr;
            float wbv = wb[o];
            float wsv = 0.f; if (LN) wsv = wsum[o];
            size_t obase = (((size_t)b * M + o) << 14) + nidx;
            float rv[4] = {0.f, 0.f, 0.f, 0.f};
            if (RES) {
                float4 rr = *(const float4*)(resid + obase);
                rv[0] = rr.x; rv[1] = rr.y; rv[2] = rr.z; rv[3] = rr.w;
            }
            float vo[4];
            #pragma unroll
            for (int r = 0; r < 4; ++r) {
                float a = acc[m][n][r];
                float v = LN ? (rsv[r] * a - muv[r] * rsv[r] * wsv + wbv) : (a + wbv);
                if (ACT == 1) v = 0.5f * v * (1.f + erff(v * 0.70710678118654752f));
                vo[r] = v + rv[r];
            }
            if (OBF) {
                ushort4 u;
                u.x = f2bf(vo[0]); u.y = f2bf(vo[1]); u.z = f2bf(vo[2]); u.w = f2bf(vo[3]);
                *(ushort4*)((unsigned short*)outv + obase) = u;
            } else {
                float4 f = {vo[0], vo[1], vo[2], vo[3]};
                *(float4*)((float*)outv + obase) = f;
            }
        }
    }
}

// ============================================================
// MFMA attention (unchanged from round 4)
// ============================================================
__global__ __launch_bounds__(64) void attn_mfma_k(const unsigned short* __restrict__ qkv,
                                                  const float* __restrict__ rpb,
                                                  const float* __restrict__ temp,
                                                  float* __restrict__ o_win, float* __restrict__ s_win) {
    __shared__ unsigned short p_lds[64 * 72];
    __shared__ float rp[225];
    int wh = blockIdx.x;
    int head = wh % HEADS;
    int bw = wh / HEADS;
    int b = bw / LWIN, l = bw % LWIN;
    int sh = l / LH, sw = l % LH;
    int h0 = sh * STR - 3, w0 = sw * STR - 3;
    int t = threadIdx.x;
    int lr = t & 15, kb = t >> 4;

    for (int i = t; i < 225; i += 64) rp[i] = rpb[i * HEADS + head];
    float tmp = temp[head];

    const size_t qbase = ((size_t)(b * 576 + head * 32)) << 14;
    const unsigned short* qp = qkv + qbase;
    const unsigned short* kp = qkv + qbase + ((size_t)192 << 14);
    const unsigned short* vp = qkv + qbase + ((size_t)384 << 14);

    bf16x8 kf[4], qf[4];
    #pragma unroll
    for (int m = 0; m < 4; ++m) {
        int jp = m * 16 + lr;
        int hh = h0 + (jp >> 3), ww = w0 + (jp & 7);
        bool ok = ((unsigned)hh < 128u) && ((unsigned)ww < 128u);
        int pix = (hh << 7) + ww;
        #pragma unroll
        for (int j = 0; j < 8; ++j) {
            unsigned short kv = 0, qv = 0;
            if (ok) {
                size_t off = ((size_t)(kb * 8 + j) << 14) + pix;
                kv = kp[off];
                qv = qp[off];
            }
            kf[m][j] = (short)kv;
            qf[m][j] = (short)qv;
        }
    }

    f32x4 st[4][4];
    #pragma unroll
    for (int m = 0; m < 4; ++m)
        #pragma unroll
        for (int n = 0; n < 4; ++n) st[m][n] = (f32x4){0.f, 0.f, 0.f, 0.f};
    #pragma unroll
    for (int m = 0; m < 4; ++m)
        #pragma unroll
        for (int n = 0; n < 4; ++n)
            st[m][n] = __builtin_amdgcn_mfma_f32_16x16x32_bf16(kf[m], qf[n], st[m][n], 0, 0, 0);

    bf16x8 vf[2][2];
    #pragma unroll
    for (int np = 0; np < 2; ++np) {
        #pragma unroll
        for (int ks = 0; ks < 2; ++ks) {
            int hh = h0 + ks * 4 + kb;
            bool okr = (unsigned)hh < 128u;
            const unsigned short* vrow = vp + (((size_t)(np * 16 + lr)) << 14) + (hh << 7) + w0;
            #pragma unroll
            for (int j = 0; j < 8; ++j) {
                int ww = w0 + j;
                unsigned short vv = 0;
                if (okr && (unsigned)ww < 128u) vv = vrow[j];
                vf[np][ks][j] = (short)vv;
            }
        }
    }

    __syncthreads();

    #pragma unroll
    for (int n = 0; n < 4; ++n) {
        int i = n * 16 + lr;
        int iyy = i >> 3, ixx = i & 7;
        #pragma unroll
        for (int m = 0; m < 4; ++m) {
            #pragma unroll
            for (int r = 0; r < 4; ++r) {
                int j = m * 16 + kb * 4 + r;
                int dy = iyy - (j >> 3) + 7;
                int dx = ixx - (j & 7) + 7;
                st[m][n][r] = st[m][n][r] * tmp + rp[dy * 15 + dx];
            }
        }
    }

    #pragma unroll
    for (int n = 0; n < 4; ++n) {
        float mx = -1e30f;
        #pragma unroll
        for (int m = 0; m < 4; ++m)
            #pragma unroll
            for (int r = 0; r < 4; ++r) mx = fmaxf(mx, st[m][n][r]);
        mx = fmaxf(mx, __shfl_xor(mx, 16));
        mx = fmaxf(mx, __shfl_xor(mx, 32));
        float s = 0.f;
        #pragma unroll
        for (int m = 0; m < 4; ++m) {
            #pragma unroll
            for (int r = 0; r < 4; ++r) {
                float e = __expf(st[m][n][r] - mx);
                st[m][n][r] = e;
                s += e;
            }
        }
        s += __shfl_xor(s, 16);
        s += __shfl_xor(s, 32);
        int i = n * 16 + lr;
        if (kb == 0) s_win[(size_t)wh * 64 + i] = s;
        #pragma unroll
        for (int m = 0; m < 4; ++m) {
            unsigned int lo = (unsigned int)f2bf(st[m][n][0]) | ((unsigned int)f2bf(st[m][n][1]) << 16);
            unsigned int hi = (unsigned int)f2bf(st[m][n][2]) | ((unsigned int)f2bf(st[m][n][3]) << 16);
            *(unsigned int*)&p_lds[i * 72 + m * 16 + kb * 4]     = lo;
            *(unsigned int*)&p_lds[i * 72 + m * 16 + kb * 4 + 2] = hi;
        }
    }

    __syncthreads();

    f32x4 oc[4][2];
    #pragma unroll
    for (int m = 0; m < 4; ++m)
        #pragma unroll
        for (int np = 0; np < 2; ++np) oc[m][np] = (f32x4){0.f, 0.f, 0.f, 0.f};
    #pragma unroll
    for (int ks = 0; ks < 2; ++ks) {
        bf16x8 pa[4];
        #pragma unroll
        for (int m = 0; m < 4; ++m)
            pa[m] = *(const bf16x8*)&p_lds[(m * 16 + lr) * 72 + ks * 32 + kb * 8];
        #pragma unroll
        for (int m = 0; m < 4; ++m)
            #pragma unroll
            for (int np = 0; np < 2; ++np)
                oc[m][np] = __builtin_amdgcn_mfma_f32_16x16x32_bf16(pa[m], vf[np][ks], oc[m][np], 0, 0, 0);
    }

    float* ob = o_win + (size_t)wh * 2048;
    #pragma unroll
    for (int m = 0; m < 4; ++m) {
        int ibase = m * 16 + kb * 4;
        #pragma unroll
        for (int np = 0; np < 2; ++np) {
            int c = np * 16 + lr;
            #pragma unroll
            for (int r = 0; r < 4; ++r)
                ob[(ibase + r) * 32 + c] = oc[m][np][r];
        }
    }
}

// ============================================================
__device__ __forceinline__ void win_range(int h, int& s0, int& s1) {
    s0 = (h + 1) / 6; if (s0 < 0) s0 = 0;
    s1 = (h + 3) / 6; if (s1 > 21) s1 = 21;
}

__global__ __launch_bounds__(256) void simg_k(const float* __restrict__ s_win, float* __restrict__ s_img) {
    int tid = blockIdx.x * 256 + threadIdx.x;
    if (tid >= B_ * HEADS * NPIX) return;
    int n = tid & (NPIX - 1);
    int bh = tid >> 14;
    int hd = bh % HEADS, b = bh / HEADS;
    int hy = n >> 7, wx = n & 127;
    int sy0, sy1, sx0, sx1;
    win_range(hy, sy0, sy1);
    win_range(wx, sx0, sx1);
    float acc = 0.f;
    for (int sy = sy0; sy <= sy1; ++sy)
        for (int sx = sx0; sx <= sx1; ++sx) {
            int idx = (hy - (sy * 6 - 3)) * 8 + (wx - (sx * 6 - 3));
            acc += s_win[(size_t)((b * LWIN + sy * LH + sx) * HEADS + hd) * 64 + idx];
        }
    s_img[tid] = acc;
}

// ============================================================
// fold o + divide -> attn_t bf16 [b][n][192]
// ============================================================
__global__ __launch_bounds__(256) void fold_k(const float* __restrict__ o_win, const float* __restrict__ s_img,
                                              unsigned short* __restrict__ attn_t) {
    int tid = blockIdx.x * 256 + threadIdx.x;
    int q = (int)((((unsigned long long)(tid >> 3)) * 174763ull) >> 19);  // tid/24
    int oct = tid - q * 24;
    int n = q & (NPIX - 1), b = q >> 14;
    int hd = oct >> 2, c8 = (oct & 3) << 3;
    int hy = n >> 7, wx = n & 127;
    int sy0, sy1, sx0, sx1;
    win_range(hy, sy0, sy1);
    win_range(wx, sx0, sx1);
    float acc[8] = {0.f, 0.f, 0.f, 0.f, 0.f, 0.f, 0.f, 0.f};
    for (int sy = sy0; sy <= sy1; ++sy)
        for (int sx = sx0; sx <= sx1; ++sx) {
            int idx = (hy - (sy * 6 - 3)) * 8 + (wx - (sx * 6 - 3));
            const float* p = o_win + ((size_t)((b * LWIN + sy * LH + sx) * HEADS + hd) * 2048 + idx * 32 + c8);
            float4 a0 = *(const float4*)p;
            float4 a1 = *(const float4*)(p + 4);
            acc[0] += a0.x; acc[1] += a0.y; acc[2] += a0.z; acc[3] += a0.w;
            acc[4] += a1.x; acc[5] += a1.y; acc[6] += a1.z; acc[7] += a1.w;
        }
    float inv = 1.f / s_img[((b * HEADS + hd) << 14) + n];
    unsigned int pk[4];
    #pragma unroll
    for (int j = 0; j < 4; ++j) {
        unsigned int lo = f2bf(acc[2 * j] * inv);
        unsigned int hi = f2bf(acc[2 * j + 1] * inv);
        pk[j] = lo | (hi << 16);
    }
    *(uint4*)&attn_t[((size_t)((b << 14) + n)) * 192 + hd * 32 + c8] = make_uint4(pk[0], pk[1], pk[2], pk[3]);
}

// ============================================================
// 2x2 average pooling
// ============================================================
__global__ __launch_bounds__(256) void halve_k(const float* __restrict__ in, float* __restrict__ out, int Win) {
    int Wo = Win >> 1;
    int tot = B_ * C_ * Wo * Wo;
    int tid = blockIdx.x * 256 + threadIdx.x;
    if (tid >= tot) return;
    int xy = tid % (Wo * Wo);
    int bc = tid / (Wo * Wo);
    int y = xy / Wo, x = xy % Wo;
    const float* p = in + (size_t)bc * Win * Win + (size_t)(2 * y) * Win + 2 * x;
    out[tid] = 0.25f * (p[0] + p[1] + p[Win] + p[Win + 1]);
}

// ============================================================
// fused HFT: a = 3*po - up(p2) - up(p4) - up(p8) staged in LDS,
// then x1 = x + sigmoid(dwconv3(a)) * po.
// grid (4 row-tiles, 192 ch, B), block 256.
// LDS tile [34][133]: row r = y - (y0-1), col c = x + 1.
// ============================================================
__global__ __launch_bounds__(256) void hft_fused_k(const float* __restrict__ po, const float* __restrict__ x,
                                                   const float* __restrict__ p2, const float* __restrict__ p4,
                                                   const float* __restrict__ p8, const float* __restrict__ hw,
                                                   const float* __restrict__ hb, float* __restrict__ x1) {
    __shared__ float tile[34 * 133];
    int rt = blockIdx.x, ch = blockIdx.y, b = blockIdx.z;
    int bc = b * C_ + ch;
    int y0 = rt << 5;
    int t = threadIdx.x;
    const float* pob = po + ((size_t)bc << 14);
    const float* p2b = p2 + ((size_t)bc << 12);
    const float* p4b = p4 + ((size_t)bc << 10);
    const float* p8b = p8 + ((size_t)bc << 8);

    for (int idx = t; idx < 34 * 133; idx += 256) {
        int row = idx / 133, col = idx - row * 133;
        int yy = y0 + row - 1, xw = col - 1;
        float val = 0.f;
        if (col < 130 && (unsigned)yy < 128u && (unsigned)xw < 128u) {
            int nn = (yy << 7) + xw;
            val = 3.f * pob[nn]
                - p2b[((yy >> 1) << 6) + (xw >> 1)]
                - p4b[((yy >> 2) << 5) + (xw >> 2)]
                - p8b[((yy >> 3) << 4) + (xw >> 3)];
        }
        tile[idx] = val;
    }
    __syncthreads();

    float wv[9];
    #pragma unroll
    for (int k = 0; k < 9; ++k) wv[k] = hw[ch * 9 + k];
    float hbv = hb[ch];

    int r = t & 31, c0 = (t >> 5) << 4;   // bank-conflict-free: 5*r mod 32 full cycle
    int nbase = ((y0 + r) << 7) + c0;
    const float* xb = x + ((size_t)bc << 14);
    float* x1b = x1 + ((size_t)bc << 14);

    float pov[16], xv[16];
    #pragma unroll
    for (int j4 = 0; j4 < 4; ++j4) {
        float4 pp = *(const float4*)(pob + nbase + 4 * j4);
        float4 xx = *(const float4*)(xb + nbase + 4 * j4);
        pov[4*j4] = pp.x; pov[4*j4+1] = pp.y; pov[4*j4+2] = pp.z; pov[4*j4+3] = pp.w;
        xv[4*j4] = xx.x;  xv[4*j4+1] = xx.y;  xv[4*j4+2] = xx.z;  xv[4*j4+3] = xx.w;
    }
    float res[16];
    #pragma unroll
    for (int j = 0; j < 16; ++j) {
        float acc = hbv;
        #pragma unroll
        for (int dy = 0; dy < 3; ++dy)
            #pragma unroll
            for (int dx = 0; dx < 3; ++dx)
                acc += wv[dy * 3 + dx] * tile[(r + dy) * 133 + c0 + j + dx];
        float sg = 1.f / (1.f + __expf(-acc));
        res[j] = xv[j] + sg * pov[j];
    }
    #pragma unroll
    for (int j4 = 0; j4 < 4; ++j4) {
        float4 o = {res[4*j4], res[4*j4+1], res[4*j4+2], res[4*j4+3]};
        *(float4*)(x1b + nbase + 4 * j4) = o;
    }
}

// ============================================================
// SimpleGate tiled: z1 *= dwconv3(LN(z2)); LN'd z2 staged in LDS.
// z = [b][768][NPIX] bf16 (z1 rows 0..383, z2 rows 384..767).
// grid (4 row-tiles, 384 ch, B), block 256.
// ============================================================
__global__ __launch_bounds__(256) void sgmul_k(unsigned short* __restrict__ z,
                                               const float* __restrict__ mu3, const float* __restrict__ rs3,
                                               const float* __restrict__ sgn_g, const float* __restrict__ sgn_b,
                                               const float* __restrict__ sg_w, const float* __restrict__ sg_b) {
    __shared__ float tile[34 * 133];
    int rt = blockIdx.x, ch = blockIdx.y, b = blockIdx.z;
    int y0 = rt << 5;
    int t = threadIdx.x;
    const unsigned short* zb = z + ((size_t)(b * 768 + 384 + ch) << 14);
    unsigned short* z1p = z + ((size_t)(b * 768 + ch) << 14);
    const float* mub = mu3 + (b << 14);
    const float* rsb = rs3 + (b << 14);
    float g = sgn_g[ch], bb = sgn_b[ch];

    for (int idx = t; idx < 34 * 133; idx += 256) {
        int row = idx / 133, col = idx - row * 133;
        int yy = y0 + row - 1, xw = col - 1;
        float val = 0.f;
        if (col < 130 && (unsigned)yy < 128u && (unsigned)xw < 128u) {
            int nn = (yy << 7) + xw;
            val = (bf2f(zb[nn]) - mub[nn]) * rsb[nn] * g + bb;
        }
        tile[idx] = val;
    }
    __syncthreads();

    float wv[9];
    #pragma unroll
    for (int k = 0; k < 9; ++k) wv[k] = sg_w[ch * 9 + k];
    float sb = sg_b[ch];

    int r = t & 31, c0 = (t >> 5) << 4;
    int nbase = ((y0 + r) << 7) + c0;

    float res[16];
    #pragma unroll
    for (int j = 0; j < 16; ++j) {
        float acc = sb;
        #pragma unroll
        for (int dy = 0; dy < 3; ++dy)
            #pragma unroll
            for (int dx = 0; dx < 3; ++dx)
                acc += wv[dy * 3 + dx] * tile[(r + dy) * 133 + c0 + j + dx];
        res[j] = acc;
    }
    uint4* zp = (uint4*)(z1p + nbase);
    uint4 v0 = zp[0], v1 = zp[1];
    unsigned int arr[8] = {v0.x, v0.y, v0.z, v0.w, v1.x, v1.y, v1.z, v1.w};
    #pragma unroll
    for (int j = 0; j < 8; ++j) {
        float lo = bf2f((unsigned short)(arr[j] & 0xFFFFu)) * res[2 * j];
        float hi = bf2f((unsigned short)(arr[j] >> 16)) * res[2 * j + 1];
        arr[j] = (unsigned int)f2bf(lo) | ((unsigned int)f2bf(hi) << 16);
    }
    zp[0] = make_uint4(arr[0], arr[1], arr[2], arr[3]);
    zp[1] = make_uint4(arr[4], arr[5], arr[6], arr[7]);
}

// ============================================================
extern "C" void kernel_launch(void* const* d_in, const int* in_sizes, int n_in,
                              void* d_out, int out_size, void* d_ws, size_t ws_size,
                              hipStream_t stream) {
    const float* x     = (const float*)d_in[0];
    const float* n1g   = (const float*)d_in[1];
    const float* n1b   = (const float*)d_in[2];
    const float* qkv_w = (const float*)d_in[3];
    const float* qkv_b = (const float*)d_in[4];
    const float* temp  = (const float*)d_in[5];
    const float* rpb   = (const float*)d_in[6];
    const float* proj_w= (const float*)d_in[7];
    const float* proj_b= (const float*)d_in[8];
    const float* hft_w = (const float*)d_in[9];
    const float* hft_b = (const float*)d_in[10];
    const float* n2g   = (const float*)d_in[11];
    const float* n2b   = (const float*)d_in[12];
    const float* fc1_w = (const float*)d_in[13];
    const float* fc1_b = (const float*)d_in[14];
    const float* sgn_g = (const float*)d_in[15];
    const float* sgn_b = (const float*)d_in[16];
    const float* sg_w  = (const float*)d_in[17];
    const float* sg_b  = (const float*)d_in[18];
    const float* fc2_w = (const float*)d_in[19];
    const float* fc2_b = (const float*)d_in[20];
    float* out = (float*)d_out;
    float* w = (float*)d_ws;

    // ---- workspace layout ----
    float* mu1 = w;            float* rs1 = w + 65536;
    float* mu2 = w + 131072;   float* rs2 = w + 196608;
    float* mu3 = w + 262144;   float* rs3 = w + 327680;
    unsigned short* wgb_qkv = (unsigned short*)(w + 393216);
    float* wsum_qkv = w + 448512;  float* wb_qkv = w + 449088;
    unsigned short* wgb_fc1 = (unsigned short*)(w + 449664);
    float* wsum_fc1 = w + 523392;  float* wb_fc1 = w + 524160;
    unsigned short* pwb  = (unsigned short*)(w + 524928);
    unsigned short* f2wb = (unsigned short*)(w + 543360);
    unsigned short* xt     = (unsigned short*)(w + 580224);
    unsigned short* attn_t = xt;
    unsigned short* qkvb = (unsigned short*)(w + 6871680);
    float* proj_out = w + 6871680;
    float* p2 = w + 19454592;  float* p4 = w + 22600320;  float* p8 = w + 23386752;
    unsigned short* x1t  = (unsigned short*)(w + 6871680);
    unsigned short* z1t  = (unsigned short*)(w + 6871680);
    float* o_win = w + 25746048;
    float* s_win = w + 49535616;
    float* s_img = w + 50279040;
    unsigned short* z = (unsigned short*)(w + 25746048);
    float* x1 = w + 50911872;

    // ---- stage A: transpose x, LN1, prep, qkv GEMM (bf16 out) ----
    transpose_k<float><<<dim3(256, 3, B_), 256, 0, stream>>>(x, xt, 192, 192 * NPIX);
    ln_stats_k<float><<<256, 256, 0, stream>>>(x, 192, 192 * NPIX, mu1, rs1);
    prep_k<<<3, 256, 0, stream>>>(qkv_w, n1g, n1b, qkv_b, 576, 192, wgb_qkv, wsum_qkv, wb_qkv);
    gemm_mfma_k<192, 128, 0, true, false, true><<<dim3(512, 9), 256, 0, stream>>>(
        wgb_qkv, xt, qkvb, mu1, rs1, wsum_qkv, wb_qkv, nullptr, 576);
    // ---- stage B: MFMA window attention ----
    attn_mfma_k<<<NWIN * HEADS, 64, 0, stream>>>(qkvb, rpb, temp, o_win, s_win);
    // ---- stage C: fold ----
    simg_k<<<1536, 256, 0, stream>>>(s_win, s_img);
    fold_k<<<6144, 256, 0, stream>>>(o_win, s_img, attn_t);
    // ---- stage D: proj GEMM (fp32 out) ----
    wcvt_k<<<144, 256, 0, stream>>>(proj_w, pwb, 192 * 192);
    gemm_mfma_k<192, 128, 0, false, false, false><<<dim3(512, 3), 256, 0, stream>>>(
        pwb, attn_t, proj_out, nullptr, nullptr, nullptr, proj_b, nullptr, 192);
    // ---- stage E: HFT + residual -> x1 (fused) ----
    halve_k<<<12288, 256, 0, stream>>>(proj_out, p2, 128);
    halve_k<<<3072, 256, 0, stream>>>(p2, p4, 64);
    halve_k<<<768, 256, 0, stream>>>(p4, p8, 32);
    hft_fused_k<<<dim3(4, 192, B_), 256, 0, stream>>>(proj_out, x, p2, p4, p8, hft_w, hft_b, x1);
    // ---- stage F: LN2 + fc1 GEMM (GELU, bf16 out z[768]) ----
    transpose_k<float><<<dim3(256, 3, B_), 256, 0, stream>>>(x1, x1t, 192, 192 * NPIX);
    ln_stats_k<float><<<256, 256, 0, stream>>>(x1, 192, 192 * NPIX, mu2, rs2);
    prep_k<<<3, 256, 0, stream>>>(fc1_w, n2g, n2b, fc1_b, 768, 192, wgb_fc1, wsum_fc1, wb_fc1);
    gemm_mfma_k<192, 128, 1, true, false, true><<<dim3(512, 12), 256, 0, stream>>>(
        wgb_fc1, x1t, z, mu2, rs2, wsum_fc1, wb_fc1, nullptr, 768);
    // ---- stage G: SimpleGate (tiled, in-place on z1 rows) ----
    ln_stats_k<unsigned short><<<256, 256, 0, stream>>>(z + (size_t)384 * NPIX, 384, 768 * NPIX, mu3, rs3);
    sgmul_k<<<dim3(4, 384, B_), 256, 0, stream>>>(z, mu3, rs3, sgn_g, sgn_b, sg_w, sg_b);
    // ---- stage H: transpose z1, fc2 GEMM + residual -> out ----
    transpose_k<unsigned short><<<dim3(256, 6, B_), 256, 0, stream>>>(z, z1t, 384, 768 * NPIX);
    wcvt_k<<<288, 256, 0, stream>>>(fc2_w, f2wb, 192 * 384);
    gemm_mfma_k<384, 64, 0, false, true, false><<<dim3(1024, 3), 256, 0, stream>>>(
        f2wb, z1t, out, nullptr, nullptr, nullptr, fc2_b, x1, 192);
}